// Round 2
// baseline (2722.318 us; speedup 1.0000x reference)
//
#include <hip/hip_runtime.h>
#include <math.h>

#define N_NODES 100000
#define N_EDGES 1600000
#define DIM 128
#define NCLS 40

typedef unsigned short u16;

// bf16 <-> f32 (round-to-nearest-even; inputs are finite)
__device__ __forceinline__ float b2f(u16 u) {
    union { unsigned int i; float f; } c; c.i = ((unsigned int)u) << 16; return c.f;
}
__device__ __forceinline__ u16 f2b(float f) {
    union { float f; unsigned int i; } c; c.f = f;
    unsigned int r = c.i + 0x7fffu + ((c.i >> 16) & 1u);
    return (u16)(r >> 16);
}

// ---------------- CSR build ----------------

__global__ void hist_kernel(const int* __restrict__ dst, int* __restrict__ cnt, int E) {
    int e = blockIdx.x * blockDim.x + threadIdx.x;
    if (e < E) atomicAdd(&cnt[dst[e]], 1);
}

__global__ void scan_blocks(const int* __restrict__ in, int* __restrict__ out,
                            int* __restrict__ bsums, int n) {
    __shared__ int s[256];
    int i = blockIdx.x * 256 + threadIdx.x;
    int v = (i < n) ? in[i] : 0;
    s[threadIdx.x] = v;
    __syncthreads();
    for (int d = 1; d < 256; d <<= 1) {
        int t = (threadIdx.x >= d) ? s[threadIdx.x - d] : 0;
        __syncthreads();
        s[threadIdx.x] += t;
        __syncthreads();
    }
    if (i < n) out[i] = s[threadIdx.x] - v;           // exclusive within block
    if (threadIdx.x == 255) bsums[blockIdx.x] = s[255];
}

__global__ void scan_small(int* data, int n) {
    __shared__ int s[512];
    int v = (threadIdx.x < n) ? data[threadIdx.x] : 0;
    s[threadIdx.x] = v;
    __syncthreads();
    for (int d = 1; d < 512; d <<= 1) {
        int t = (threadIdx.x >= d) ? s[threadIdx.x - d] : 0;
        __syncthreads();
        s[threadIdx.x] += t;
        __syncthreads();
    }
    if (threadIdx.x < n) data[threadIdx.x] = s[threadIdx.x] - v;   // exclusive
}

__global__ void add_offsets(int* __restrict__ rs, const int* __restrict__ bsums,
                            int n, int total) {
    int i = blockIdx.x * 256 + threadIdx.x;
    if (i < n) rs[i] += bsums[blockIdx.x];
    if (blockIdx.x == 0 && threadIdx.x == 0) rs[n] = total;
}

// stores perm[src] when perm != nullptr (folds aggr_b row-permutation into indices)
__global__ void scatter_kernel(const int* __restrict__ src, const int* __restrict__ dst,
                               const int* __restrict__ rs, int* __restrict__ cursor,
                               int* __restrict__ ss, const int* __restrict__ perm, int E) {
    int e = blockIdx.x * blockDim.x + threadIdx.x;
    if (e >= E) return;
    int d = dst[e];
    int p = atomicAdd(&cursor[d], 1);
    int s = src[e];
    if (perm) s = perm[s];
    ss[rs[d] + p] = s;
}

// ---------------- fused aggregate + linear kernels ----------------
// 256 threads = 8 node-groups of 32 lanes. Aggregation lands in LDS (wave-local,
// no barrier needed: each group's LDS slice is written & read by the same wave).

// A = relu(mean_agg(src)@Wl + src@Wr + bl)     (pre-aggregation passes)
template<bool SRC_BF16>
__global__ __launch_bounds__(256) void sage_pre(
        const void* __restrict__ srcv,
        const int* __restrict__ rs, const int* __restrict__ ss,
        const float* __restrict__ Wl, const float* __restrict__ Wr,
        const float* __restrict__ bl, u16* __restrict__ out)
{
    __shared__ float T[8][DIM];
    __shared__ float Xd[8][DIM];
    const int g = threadIdx.x >> 5;
    const int lane = threadIdx.x & 31;
    const int n = blockIdx.x * 8 + g;
    const int f0 = lane * 4;

    float ax = 0, ay = 0, az = 0, aw = 0;
    int beg = rs[n], end = rs[n + 1];
    #pragma unroll 2
    for (int e = beg; e < end; ++e) {
        int s = ss[e];
        if (SRC_BF16) {
            ushort4 v = *(const ushort4*)((const u16*)srcv + (size_t)s * DIM + f0);
            ax += b2f(v.x); ay += b2f(v.y); az += b2f(v.z); aw += b2f(v.w);
        } else {
            float4 v = *(const float4*)((const float*)srcv + (size_t)s * DIM + f0);
            ax += v.x; ay += v.y; az += v.z; aw += v.w;
        }
    }
    float inv = (end > beg) ? 1.f / (float)(end - beg) : 0.f;
    T[g][f0 + 0] = ax * inv; T[g][f0 + 1] = ay * inv;
    T[g][f0 + 2] = az * inv; T[g][f0 + 3] = aw * inv;
    if (SRC_BF16) {
        ushort4 v = *(const ushort4*)((const u16*)srcv + (size_t)n * DIM + f0);
        Xd[g][f0 + 0] = b2f(v.x); Xd[g][f0 + 1] = b2f(v.y);
        Xd[g][f0 + 2] = b2f(v.z); Xd[g][f0 + 3] = b2f(v.w);
    } else {
        float4 v = *(const float4*)((const float*)srcv + (size_t)n * DIM + f0);
        Xd[g][f0 + 0] = v.x; Xd[g][f0 + 1] = v.y;
        Xd[g][f0 + 2] = v.z; Xd[g][f0 + 3] = v.w;
    }
    // wave-local LDS: write->read ordering guaranteed within the wave
    float a0 = 0, a1 = 0, a2 = 0, a3 = 0, s0 = 0, s1 = 0, s2 = 0, s3 = 0;
    const int h0 = f0;
    #pragma unroll 4
    for (int k = 0; k < DIM; ++k) {
        float tv = T[g][k], xv = Xd[g][k];
        float4 wl = *(const float4*)(Wl + k * DIM + h0);
        float4 wr = *(const float4*)(Wr + k * DIM + h0);
        a0 += tv * wl.x; a1 += tv * wl.y; a2 += tv * wl.z; a3 += tv * wl.w;
        s0 += xv * wr.x; s1 += xv * wr.y; s2 += xv * wr.z; s3 += xv * wr.w;
    }
    float4 bb = *(const float4*)(bl + h0);
    ushort4 o;
    o.x = f2b(fmaxf(a0 + s0 + bb.x, 0.f));
    o.y = f2b(fmaxf(a1 + s1 + bb.y, 0.f));
    o.z = f2b(fmaxf(a2 + s2 + bb.z, 0.f));
    o.w = f2b(fmaxf(a3 + s3 + bb.w, 0.f));
    *(ushort4*)(out + (size_t)n * DIM + h0) = o;
}

// xm_new = r*relu(agg_a@Wl + b + S) + (1-r)*relu(agg_b@Wl + b + S), S = xm@Wr (shared)
template<bool SRC_BF16>
__global__ __launch_bounds__(256) void sage_main(
        const void* __restrict__ srcv, const u16* __restrict__ xm,
        const int* __restrict__ rs_a, const int* __restrict__ ss_a,
        const int* __restrict__ rs_b, const int* __restrict__ ss_b,
        const float* __restrict__ Wl, const float* __restrict__ Wr,
        const float* __restrict__ bl, const float* __restrict__ rp,
        u16* __restrict__ out)
{
    __shared__ float Tl[8][DIM];
    __shared__ float Tb[8][DIM];
    __shared__ float Xm[8][DIM];
    const int g = threadIdx.x >> 5;
    const int lane = threadIdx.x & 31;
    const int n = blockIdx.x * 8 + g;
    const int f0 = lane * 4;

    {   // branch-a aggregation
        float ax = 0, ay = 0, az = 0, aw = 0;
        int beg = rs_a[n], end = rs_a[n + 1];
        #pragma unroll 2
        for (int e = beg; e < end; ++e) {
            int s = ss_a[e];
            if (SRC_BF16) {
                ushort4 v = *(const ushort4*)((const u16*)srcv + (size_t)s * DIM + f0);
                ax += b2f(v.x); ay += b2f(v.y); az += b2f(v.z); aw += b2f(v.w);
            } else {
                float4 v = *(const float4*)((const float*)srcv + (size_t)s * DIM + f0);
                ax += v.x; ay += v.y; az += v.z; aw += v.w;
            }
        }
        float inv = (end > beg) ? 1.f / (float)(end - beg) : 0.f;
        Tl[g][f0 + 0] = ax * inv; Tl[g][f0 + 1] = ay * inv;
        Tl[g][f0 + 2] = az * inv; Tl[g][f0 + 3] = aw * inv;
    }
    {   // branch-b aggregation (perm already folded into ss_b)
        float ax = 0, ay = 0, az = 0, aw = 0;
        int beg = rs_b[n], end = rs_b[n + 1];
        #pragma unroll 2
        for (int e = beg; e < end; ++e) {
            int s = ss_b[e];
            if (SRC_BF16) {
                ushort4 v = *(const ushort4*)((const u16*)srcv + (size_t)s * DIM + f0);
                ax += b2f(v.x); ay += b2f(v.y); az += b2f(v.z); aw += b2f(v.w);
            } else {
                float4 v = *(const float4*)((const float*)srcv + (size_t)s * DIM + f0);
                ax += v.x; ay += v.y; az += v.z; aw += v.w;
            }
        }
        float inv = (end > beg) ? 1.f / (float)(end - beg) : 0.f;
        Tb[g][f0 + 0] = ax * inv; Tb[g][f0 + 1] = ay * inv;
        Tb[g][f0 + 2] = az * inv; Tb[g][f0 + 3] = aw * inv;
    }
    {   // xm row
        ushort4 v = *(const ushort4*)(xm + (size_t)n * DIM + f0);
        Xm[g][f0 + 0] = b2f(v.x); Xm[g][f0 + 1] = b2f(v.y);
        Xm[g][f0 + 2] = b2f(v.z); Xm[g][f0 + 3] = b2f(v.w);
    }
    float a[4] = {0, 0, 0, 0}, b[4] = {0, 0, 0, 0}, sv[4] = {0, 0, 0, 0};
    const int h0 = f0;
    #pragma unroll 4
    for (int k = 0; k < DIM; ++k) {
        float tl = Tl[g][k], tb = Tb[g][k], mv = Xm[g][k];
        float4 wl = *(const float4*)(Wl + k * DIM + h0);
        float4 wr = *(const float4*)(Wr + k * DIM + h0);
        a[0] += tl * wl.x; a[1] += tl * wl.y; a[2] += tl * wl.z; a[3] += tl * wl.w;
        b[0] += tb * wl.x; b[1] += tb * wl.y; b[2] += tb * wl.z; b[3] += tb * wl.w;
        sv[0] += mv * wr.x; sv[1] += mv * wr.y; sv[2] += mv * wr.z; sv[3] += mv * wr.w;
    }
    float r = *rp;
    float4 bb = *(const float4*)(bl + h0);
    float bias[4] = {bb.x, bb.y, bb.z, bb.w};
    ushort4 o;
    u16* op = (u16*)&o;
    #pragma unroll
    for (int j = 0; j < 4; ++j) {
        float v  = fmaxf(a[j] + sv[j] + bias[j], 0.f);
        float vb = fmaxf(b[j] + sv[j] + bias[j], 0.f);
        op[j] = f2b(r * v + (1.f - r) * vb);
    }
    *(ushort4*)(out + (size_t)n * DIM + h0) = o;
}

// xm0 = r*x + (1-r)*x[perm]   (bf16 out)
__global__ void mix_init(const float* __restrict__ x, const int* __restrict__ perm,
                         const float* __restrict__ rp, u16* __restrict__ out) {
    int i = blockIdx.x * 256 + threadIdx.x;     // over N*DIM
    int n = i >> 7, f = i & 127;
    float r = *rp;
    int p = perm[n];
    out[i] = f2b(r * x[i] + (1.f - r) * x[(size_t)p * DIM + f]);
}

// logits = xm @ W_out + b_out ; out = log_softmax(logits)  — one wave per node
__global__ __launch_bounds__(64) void out_kernel(const u16* __restrict__ xm,
        const float* __restrict__ Wo, const float* __restrict__ bo,
        float* __restrict__ out) {
    __shared__ float row[DIM];
    int n = blockIdx.x;
    int h = threadIdx.x;
    row[h]      = b2f(xm[(size_t)n * DIM + h]);
    row[h + 64] = b2f(xm[(size_t)n * DIM + h + 64]);
    // single wave: LDS write->read ordered within the wave
    float acc = -1e30f;
    if (h < NCLS) {
        acc = bo[h];
        #pragma unroll 4
        for (int k = 0; k < DIM; ++k) acc += row[k] * Wo[k * NCLS + h];
    }
    float m = acc;
    for (int o = 32; o > 0; o >>= 1) m = fmaxf(m, __shfl_xor(m, o, 64));
    float e = (h < NCLS) ? expf(acc - m) : 0.f;
    float sum = e;
    for (int o = 32; o > 0; o >>= 1) sum += __shfl_xor(sum, o, 64);
    if (h < NCLS) out[(size_t)n * NCLS + h] = acc - m - logf(sum);
}

// ---------------- driver ----------------

extern "C" void kernel_launch(void* const* d_in, const int* in_sizes, int n_in,
                              void* d_out, int out_size, void* d_ws, size_t ws_size,
                              hipStream_t stream) {
    const float* x    = (const float*)d_in[0];
    const float* Wl   = (const float*)d_in[1];   // [3][128][128]
    const float* bl   = (const float*)d_in[2];   // [3][128]
    const float* Wr   = (const float*)d_in[3];   // [3][128][128]
    const float* Wo   = (const float*)d_in[4];   // [128][40]
    const float* bo   = (const float*)d_in[5];   // [40]
    const float* rp   = (const float*)d_in[6];   // scalar mix_ratio
    const int*   adj  = (const int*)d_in[7];     // [2][E]
    const int*   adjb = (const int*)d_in[8];     // [2][E]
    const int*   perm = (const int*)d_in[9];     // [N]
    float* out = (float*)d_out;

    char* ws = (char*)d_ws;
    size_t off = 0;
    auto alloc = [&](size_t bytes) {
        char* p = ws + off;
        off += (bytes + 255) & ~(size_t)255;
        return p;
    };
    int* rs_a   = (int*)alloc((N_NODES + 1) * 4);
    int* rs_b   = (int*)alloc((N_NODES + 1) * 4);
    int* ss_a   = (int*)alloc((size_t)N_EDGES * 4);
    int* ss_b   = (int*)alloc((size_t)N_EDGES * 4);
    int* cursor = (int*)alloc((size_t)N_NODES * 4);
    int* bsums  = (int*)alloc(512 * 4);
    const size_t FB = (size_t)N_NODES * DIM * 2;   // bf16 feature buffer
    u16* A1  = (u16*)alloc(FB);
    u16* A2  = (u16*)alloc(FB);
    u16* xm0 = (u16*)alloc(FB);
    u16* xm1 = (u16*)alloc(FB);
    // total ws use ~117 MB

    const int nbE = (N_EDGES + 255) / 256;
    const int nbN = (N_NODES + 255) / 256;   // 391

    // CSR for adj
    hipMemsetAsync(cursor, 0, (size_t)N_NODES * 4, stream);
    hist_kernel<<<nbE, 256, 0, stream>>>(adj + N_EDGES, cursor, N_EDGES);
    scan_blocks<<<nbN, 256, 0, stream>>>(cursor, rs_a, bsums, N_NODES);
    scan_small<<<1, 512, 0, stream>>>(bsums, nbN);
    add_offsets<<<nbN, 256, 0, stream>>>(rs_a, bsums, N_NODES, N_EDGES);
    hipMemsetAsync(cursor, 0, (size_t)N_NODES * 4, stream);
    scatter_kernel<<<nbE, 256, 0, stream>>>(adj, adj + N_EDGES, rs_a, cursor, ss_a,
                                            nullptr, N_EDGES);

    // CSR for adj_b, with perm folded into stored sources
    hipMemsetAsync(cursor, 0, (size_t)N_NODES * 4, stream);
    hist_kernel<<<nbE, 256, 0, stream>>>(adjb + N_EDGES, cursor, N_EDGES);
    scan_blocks<<<nbN, 256, 0, stream>>>(cursor, rs_b, bsums, N_NODES);
    scan_small<<<1, 512, 0, stream>>>(bsums, nbN);
    add_offsets<<<nbN, 256, 0, stream>>>(rs_b, bsums, N_NODES, N_EDGES);
    hipMemsetAsync(cursor, 0, (size_t)N_NODES * 4, stream);
    scatter_kernel<<<nbE, 256, 0, stream>>>(adjb, adjb + N_EDGES, rs_b, cursor, ss_b,
                                            perm, N_EDGES);

    const int WD = DIM * DIM;   // per-layer weight stride
    const int nbG = N_NODES / 8;   // 12500 blocks, 8 nodes each

    // pre-aggregation passes: A1 = relu(sage(x,x)), A2 = relu(sage(A1,A1))
    sage_pre<false><<<nbG, 256, 0, stream>>>(x, rs_a, ss_a, Wl, Wr, bl, A1);
    sage_pre<true><<<nbG, 256, 0, stream>>>(A1, rs_a, ss_a, Wl + WD, Wr + WD,
                                            bl + DIM, A2);

    // x_mix init
    mix_init<<<(N_NODES * DIM) / 256, 256, 0, stream>>>(x, perm, rp, xm0);

    // dual-branch propagation (fused agg_a + agg_b + lin)
    sage_main<false><<<nbG, 256, 0, stream>>>(x, xm0, rs_a, ss_a, rs_b, ss_b,
        Wl, Wr, bl, rp, xm1);
    sage_main<true><<<nbG, 256, 0, stream>>>(A1, xm1, rs_a, ss_a, rs_b, ss_b,
        Wl + WD, Wr + WD, bl + DIM, rp, xm0);
    sage_main<true><<<nbG, 256, 0, stream>>>(A2, xm0, rs_a, ss_a, rs_b, ss_b,
        Wl + 2 * WD, Wr + 2 * WD, bl + 2 * DIM, rp, xm1);

    // logits + log_softmax
    out_kernel<<<N_NODES, 64, 0, stream>>>(xm1, Wo, bo, out);
}

// Round 3
// 2159.894 us; speedup vs baseline: 1.2604x; 1.2604x over previous
//
#include <hip/hip_runtime.h>
#include <math.h>

#define N_NODES 100000
#define N_EDGES 1600000
#define DIM 128
#define NCLS 40

typedef unsigned short u16;
typedef unsigned int u32;

__device__ __forceinline__ float b2f(u16 u){ union{u32 i;float f;}c; c.i=((u32)u)<<16; return c.f; }
__device__ __forceinline__ float b2f_lo(u32 u){ union{u32 i;float f;}c; c.i=u<<16; return c.f; }
__device__ __forceinline__ float b2f_hi(u32 u){ union{u32 i;float f;}c; c.i=u&0xffff0000u; return c.f; }
__device__ __forceinline__ u16 f2b(float f){ union{float f;u32 i;}c; c.f=f; u32 r=c.i+0x7fffu+((c.i>>16)&1u); return (u16)(r>>16); }
__device__ __forceinline__ u32 pack2(float lo, float hi){ return ((u32)f2b(lo)) | (((u32)f2b(hi))<<16); }

// ---------------- CSR build ----------------

__global__ void hist_kernel(const int* __restrict__ dst, int* __restrict__ cnt, int E) {
    int e = blockIdx.x * blockDim.x + threadIdx.x;
    if (e < E) atomicAdd(&cnt[dst[e]], 1);
}

__global__ void scan_blocks(const int* __restrict__ in, int* __restrict__ out,
                            int* __restrict__ bsums, int n) {
    __shared__ int s[256];
    int i = blockIdx.x * 256 + threadIdx.x;
    int v = (i < n) ? in[i] : 0;
    s[threadIdx.x] = v;
    __syncthreads();
    for (int d = 1; d < 256; d <<= 1) {
        int t = (threadIdx.x >= d) ? s[threadIdx.x - d] : 0;
        __syncthreads();
        s[threadIdx.x] += t;
        __syncthreads();
    }
    if (i < n) out[i] = s[threadIdx.x] - v;
    if (threadIdx.x == 255) bsums[blockIdx.x] = s[255];
}

__global__ void scan_small(int* data, int n) {
    __shared__ int s[512];
    int v = (threadIdx.x < n) ? data[threadIdx.x] : 0;
    s[threadIdx.x] = v;
    __syncthreads();
    for (int d = 1; d < 512; d <<= 1) {
        int t = (threadIdx.x >= d) ? s[threadIdx.x - d] : 0;
        __syncthreads();
        s[threadIdx.x] += t;
        __syncthreads();
    }
    if (threadIdx.x < n) data[threadIdx.x] = s[threadIdx.x] - v;
}

__global__ void add_offsets(int* __restrict__ rs, const int* __restrict__ bsums,
                            int n, int total) {
    int i = blockIdx.x * 256 + threadIdx.x;
    if (i < n) rs[i] += bsums[blockIdx.x];
    if (blockIdx.x == 0 && threadIdx.x == 0) rs[n] = total;
}

__global__ void scatter_kernel(const int* __restrict__ src, const int* __restrict__ dst,
                               const int* __restrict__ rs, int* __restrict__ cursor,
                               int* __restrict__ ss, const int* __restrict__ perm, int E) {
    int e = blockIdx.x * blockDim.x + threadIdx.x;
    if (e >= E) return;
    int d = dst[e];
    int p = atomicAdd(&cursor[d], 1);
    int s = src[e];
    if (perm) s = perm[s];
    ss[rs[d] + p] = s;
}

// xb = bf16(x); xm0 = bf16(r*x + (1-r)*x[perm])
__global__ void conv_mix(const float* __restrict__ x, const int* __restrict__ perm,
                         const float* __restrict__ rp, u16* __restrict__ xb,
                         u16* __restrict__ xm) {
    int i = blockIdx.x * 256 + threadIdx.x;
    int n = i >> 7, f = i & 127;
    float xv = x[i];
    float r = *rp;
    int p = perm[n];
    xb[i] = f2b(xv);
    xm[i] = f2b(r * xv + (1.f - r) * x[(size_t)p * DIM + f]);
}

// ---------------- gather: 16 lanes x 16B cover one 256B row; 4 edges/wave-load ----

__device__ __forceinline__ void gather_row(const u16* __restrict__ src,
        const int* __restrict__ ss, int beg, int end, int lane,
        float* __restrict__ ldsrow, u16* __restrict__ gout) {
    const int sub = lane >> 4;          // 0..3: which edge of the quad
    const int fo = (lane & 15) * 8;     // 8 bf16 features per lane
    float acc[8] = {0,0,0,0,0,0,0,0};
    #pragma unroll 2
    for (int e = beg + sub; e < end; e += 4) {
        int s = ss[e];
        uint4 v = *(const uint4*)(src + (size_t)s * DIM + fo);
        acc[0] += b2f_lo(v.x); acc[1] += b2f_hi(v.x);
        acc[2] += b2f_lo(v.y); acc[3] += b2f_hi(v.y);
        acc[4] += b2f_lo(v.z); acc[5] += b2f_hi(v.z);
        acc[6] += b2f_lo(v.w); acc[7] += b2f_hi(v.w);
    }
    #pragma unroll
    for (int j = 0; j < 8; ++j) {
        acc[j] += __shfl_xor(acc[j], 16, 64);
        acc[j] += __shfl_xor(acc[j], 32, 64);
    }
    float inv = (end > beg) ? 1.f / (float)(end - beg) : 0.f;
    #pragma unroll
    for (int j = 0; j < 8; ++j) acc[j] *= inv;
    if (sub == 0) {
        float4 lo4 = {acc[0], acc[1], acc[2], acc[3]};
        float4 hi4 = {acc[4], acc[5], acc[6], acc[7]};
        *(float4*)(ldsrow + fo) = lo4;
        *(float4*)(ldsrow + fo + 4) = hi4;
        if (gout) {
            uint4 p;
            p.x = pack2(acc[0], acc[1]); p.y = pack2(acc[2], acc[3]);
            p.z = pack2(acc[4], acc[5]); p.w = pack2(acc[6], acc[7]);
            *(uint4*)(gout + fo) = p;
        }
    }
}

// coalesced bf16 row -> fp32 LDS row (64 lanes x 2 feats)
__device__ __forceinline__ void load_row(const u16* __restrict__ row, int lane,
                                         float* __restrict__ ldsrow) {
    u32 v = *(const u32*)(row + lane * 2);
    ldsrow[lane * 2]     = b2f_lo(v);
    ldsrow[lane * 2 + 1] = b2f_hi(v);
}

// ---------------- fused sage kernels: block=16 nodes, wave=4 nodes --------------
// All LDS traffic is wave-local (written & read by the same wave): no barriers.

// A = relu(agg@Wl + X@Wr + bl); also writes agg (bf16) to Tout for reuse
__global__ __launch_bounds__(256) void sage_pre(
        const u16* __restrict__ src, const int* __restrict__ rs, const int* __restrict__ ss,
        const float* __restrict__ Wl, const float* __restrict__ Wr,
        const float* __restrict__ bl, u16* __restrict__ A, u16* __restrict__ Tout)
{
    __shared__ float Tl[16][DIM];
    __shared__ float Xd[16][DIM];
    const int wave = threadIdx.x >> 6;
    const int lane = threadIdx.x & 63;
    const int nb = blockIdx.x * 16 + wave * 4;

    for (int m = 0; m < 4; ++m) {
        int n = nb + m;
        gather_row(src, ss, rs[n], rs[n + 1], lane, Tl[wave * 4 + m],
                   Tout + (size_t)n * DIM);
        load_row(src + (size_t)n * DIM, lane, Xd[wave * 4 + m]);
    }

    const int half = lane >> 5;
    const int c4 = (lane & 31) * 4;
    const int m0 = wave * 4 + half * 2, m1 = m0 + 1;
    float a0[4] = {0,0,0,0}, a1[4] = {0,0,0,0};
    float s0[4] = {0,0,0,0}, s1[4] = {0,0,0,0};
    #pragma unroll 2
    for (int k = 0; k < DIM; k += 4) {
        float t0[4], t1[4], x0[4], x1[4];
        *(float4*)t0 = *(const float4*)(&Tl[m0][k]);
        *(float4*)t1 = *(const float4*)(&Tl[m1][k]);
        *(float4*)x0 = *(const float4*)(&Xd[m0][k]);
        *(float4*)x1 = *(const float4*)(&Xd[m1][k]);
        #pragma unroll
        for (int kk = 0; kk < 4; ++kk) {
            float wl[4], wr[4];
            *(float4*)wl = *(const float4*)(Wl + (k + kk) * DIM + c4);
            *(float4*)wr = *(const float4*)(Wr + (k + kk) * DIM + c4);
            #pragma unroll
            for (int c = 0; c < 4; ++c) {
                a0[c] += t0[kk] * wl[c]; a1[c] += t1[kk] * wl[c];
                s0[c] += x0[kk] * wr[c]; s1[c] += x1[kk] * wr[c];
            }
        }
    }
    float bb[4]; *(float4*)bb = *(const float4*)(bl + c4);
    const int n0 = nb + half * 2, n1 = n0 + 1;
    ushort4 o0, o1;
    u16* o0p = (u16*)&o0; u16* o1p = (u16*)&o1;
    #pragma unroll
    for (int c = 0; c < 4; ++c) {
        o0p[c] = f2b(fmaxf(a0[c] + s0[c] + bb[c], 0.f));
        o1p[c] = f2b(fmaxf(a1[c] + s1[c] + bb[c], 0.f));
    }
    *(ushort4*)(A + (size_t)n0 * DIM + c4) = o0;
    *(ushort4*)(A + (size_t)n1 * DIM + c4) = o1;
}

// xm_new = r*relu(Ta@Wl+b+S) + (1-r)*relu(Tb@Wl+b+S), S = xm@Wr
// Ta from Tpre (GATHER_A=false) or gathered over ss_a (GATHER_A=true)
template<bool GATHER_A>
__global__ __launch_bounds__(256) void sage_main(
        const u16* __restrict__ src, const u16* __restrict__ Tpre,
        const u16* __restrict__ xm,
        const int* __restrict__ rs_a, const int* __restrict__ ss_a,
        const int* __restrict__ rs_b, const int* __restrict__ ss_b,
        const float* __restrict__ Wl, const float* __restrict__ Wr,
        const float* __restrict__ bl, const float* __restrict__ rp,
        u16* __restrict__ xout)
{
    __shared__ float Tl[16][DIM];
    __shared__ float Tb[16][DIM];
    __shared__ float Xm[16][DIM];
    const int wave = threadIdx.x >> 6;
    const int lane = threadIdx.x & 63;
    const int nb = blockIdx.x * 16 + wave * 4;

    for (int m = 0; m < 4; ++m) {
        int n = nb + m;
        if (GATHER_A)
            gather_row(src, ss_a, rs_a[n], rs_a[n + 1], lane, Tl[wave * 4 + m], nullptr);
        else
            load_row(Tpre + (size_t)n * DIM, lane, Tl[wave * 4 + m]);
        gather_row(src, ss_b, rs_b[n], rs_b[n + 1], lane, Tb[wave * 4 + m], nullptr);
        load_row(xm + (size_t)n * DIM, lane, Xm[wave * 4 + m]);
    }

    const int half = lane >> 5;
    const int c4 = (lane & 31) * 4;
    const int m0 = wave * 4 + half * 2, m1 = m0 + 1;
    float a0[4] = {0,0,0,0}, a1[4] = {0,0,0,0};
    float b0[4] = {0,0,0,0}, b1[4] = {0,0,0,0};
    float s0[4] = {0,0,0,0}, s1[4] = {0,0,0,0};
    #pragma unroll 2
    for (int k = 0; k < DIM; k += 4) {
        float t0[4], t1[4], u0[4], u1[4], x0[4], x1[4];
        *(float4*)t0 = *(const float4*)(&Tl[m0][k]);
        *(float4*)t1 = *(const float4*)(&Tl[m1][k]);
        *(float4*)u0 = *(const float4*)(&Tb[m0][k]);
        *(float4*)u1 = *(const float4*)(&Tb[m1][k]);
        *(float4*)x0 = *(const float4*)(&Xm[m0][k]);
        *(float4*)x1 = *(const float4*)(&Xm[m1][k]);
        #pragma unroll
        for (int kk = 0; kk < 4; ++kk) {
            float wl[4], wr[4];
            *(float4*)wl = *(const float4*)(Wl + (k + kk) * DIM + c4);
            *(float4*)wr = *(const float4*)(Wr + (k + kk) * DIM + c4);
            #pragma unroll
            for (int c = 0; c < 4; ++c) {
                a0[c] += t0[kk] * wl[c]; a1[c] += t1[kk] * wl[c];
                b0[c] += u0[kk] * wl[c]; b1[c] += u1[kk] * wl[c];
                s0[c] += x0[kk] * wr[c]; s1[c] += x1[kk] * wr[c];
            }
        }
    }
    float r = *rp;
    float bb[4]; *(float4*)bb = *(const float4*)(bl + c4);
    const int n0 = nb + half * 2, n1 = n0 + 1;
    ushort4 o0, o1;
    u16* o0p = (u16*)&o0; u16* o1p = (u16*)&o1;
    #pragma unroll
    for (int c = 0; c < 4; ++c) {
        float v0  = fmaxf(a0[c] + s0[c] + bb[c], 0.f);
        float vb0 = fmaxf(b0[c] + s0[c] + bb[c], 0.f);
        float v1  = fmaxf(a1[c] + s1[c] + bb[c], 0.f);
        float vb1 = fmaxf(b1[c] + s1[c] + bb[c], 0.f);
        o0p[c] = f2b(r * v0 + (1.f - r) * vb0);
        o1p[c] = f2b(r * v1 + (1.f - r) * vb1);
    }
    *(ushort4*)(xout + (size_t)n0 * DIM + c4) = o0;
    *(ushort4*)(xout + (size_t)n1 * DIM + c4) = o1;
}

// logits + log_softmax; 4 waves/block, one node per wave
__global__ __launch_bounds__(256) void out_kernel(const u16* __restrict__ xm,
        const float* __restrict__ Wo, const float* __restrict__ bo,
        float* __restrict__ out) {
    __shared__ float row[4][DIM];
    const int wave = threadIdx.x >> 6;
    const int lane = threadIdx.x & 63;
    const int n = blockIdx.x * 4 + wave;
    load_row(xm + (size_t)n * DIM, lane, row[wave]);
    float acc = -1e30f;
    if (lane < NCLS) {
        acc = bo[lane];
        #pragma unroll 4
        for (int k = 0; k < DIM; ++k) acc += row[wave][k] * Wo[k * NCLS + lane];
    }
    float m = acc;
    for (int o = 32; o > 0; o >>= 1) m = fmaxf(m, __shfl_xor(m, o, 64));
    float e = (lane < NCLS) ? expf(acc - m) : 0.f;
    float sum = e;
    for (int o = 32; o > 0; o >>= 1) sum += __shfl_xor(sum, o, 64);
    if (lane < NCLS) out[(size_t)n * NCLS + lane] = acc - m - logf(sum);
}

// ---------------- driver ----------------

extern "C" void kernel_launch(void* const* d_in, const int* in_sizes, int n_in,
                              void* d_out, int out_size, void* d_ws, size_t ws_size,
                              hipStream_t stream) {
    const float* x    = (const float*)d_in[0];
    const float* Wl   = (const float*)d_in[1];
    const float* bl   = (const float*)d_in[2];
    const float* Wr   = (const float*)d_in[3];
    const float* Wo   = (const float*)d_in[4];
    const float* bo   = (const float*)d_in[5];
    const float* rp   = (const float*)d_in[6];
    const int*   adj  = (const int*)d_in[7];
    const int*   adjb = (const int*)d_in[8];
    const int*   perm = (const int*)d_in[9];
    float* out = (float*)d_out;

    char* ws = (char*)d_ws;
    size_t off = 0;
    auto alloc = [&](size_t bytes) {
        char* p = ws + off;
        off += (bytes + 255) & ~(size_t)255;
        return p;
    };
    int* rs_a   = (int*)alloc((N_NODES + 1) * 4);
    int* rs_b   = (int*)alloc((N_NODES + 1) * 4);
    int* ss_a   = (int*)alloc((size_t)N_EDGES * 4);
    int* ss_b   = (int*)alloc((size_t)N_EDGES * 4);
    int* cursor = (int*)alloc((size_t)N_NODES * 4);
    int* bsums  = (int*)alloc(512 * 4);
    const size_t FB = (size_t)N_NODES * DIM * 2;   // bf16 feature buffer (25.6 MB)
    u16* xb  = (u16*)alloc(FB);
    u16* xm0 = (u16*)alloc(FB);
    u16* A1  = (u16*)alloc(FB);
    u16* A2  = (u16*)alloc(FB);
    u16* T0  = (u16*)alloc(FB);    // aliased as xm1 (row-for-row safe, see below)
    u16* T1  = (u16*)alloc(FB);
    u16* xm1 = T0;
    // total ws use ~168 MB

    const int nbE = (N_EDGES + 255) / 256;
    const int nbN = (N_NODES + 255) / 256;

    // CSR for adj
    hipMemsetAsync(cursor, 0, (size_t)N_NODES * 4, stream);
    hist_kernel<<<nbE, 256, 0, stream>>>(adj + N_EDGES, cursor, N_EDGES);
    scan_blocks<<<nbN, 256, 0, stream>>>(cursor, rs_a, bsums, N_NODES);
    scan_small<<<1, 512, 0, stream>>>(bsums, nbN);
    add_offsets<<<nbN, 256, 0, stream>>>(rs_a, bsums, N_NODES, N_EDGES);
    hipMemsetAsync(cursor, 0, (size_t)N_NODES * 4, stream);
    scatter_kernel<<<nbE, 256, 0, stream>>>(adj, adj + N_EDGES, rs_a, cursor, ss_a,
                                            nullptr, N_EDGES);

    // CSR for adj_b (perm folded into stored sources)
    hipMemsetAsync(cursor, 0, (size_t)N_NODES * 4, stream);
    hist_kernel<<<nbE, 256, 0, stream>>>(adjb + N_EDGES, cursor, N_EDGES);
    scan_blocks<<<nbN, 256, 0, stream>>>(cursor, rs_b, bsums, N_NODES);
    scan_small<<<1, 512, 0, stream>>>(bsums, nbN);
    add_offsets<<<nbN, 256, 0, stream>>>(rs_b, bsums, N_NODES, N_EDGES);
    hipMemsetAsync(cursor, 0, (size_t)N_NODES * 4, stream);
    scatter_kernel<<<nbE, 256, 0, stream>>>(adjb, adjb + N_EDGES, rs_b, cursor, ss_b,
                                            perm, N_EDGES);

    const int WD = DIM * DIM;
    const int nbS = N_NODES / 16;     // 6250 blocks, 16 nodes each

    // xb = bf16(x); xm0 = mix
    conv_mix<<<(N_NODES * DIM) / 256, 256, 0, stream>>>(x, perm, rp, xb, xm0);

    // pre passes; each also saves its aggregation (T0 = agg_a(xb), T1 = agg_a(A1))
    sage_pre<<<nbS, 256, 0, stream>>>(xb, rs_a, ss_a, Wl, Wr, bl, A1, T0);
    sage_pre<<<nbS, 256, 0, stream>>>(A1, rs_a, ss_a, Wl + WD, Wr + WD, bl + DIM, A2, T1);

    // main layers: 0/1 reuse T0/T1 (gather only branch-b), layer 2 gathers both.
    // xm1 aliases T0: main0 reads T0 row n before writing xm1 row n (same wave).
    sage_main<false><<<nbS, 256, 0, stream>>>(xb, T0, xm0, rs_a, ss_a, rs_b, ss_b,
        Wl, Wr, bl, rp, xm1);
    sage_main<false><<<nbS, 256, 0, stream>>>(A1, T1, xm1, rs_a, ss_a, rs_b, ss_b,
        Wl + WD, Wr + WD, bl + DIM, rp, xm0);
    sage_main<true><<<nbS, 256, 0, stream>>>(A2, nullptr, xm0, rs_a, ss_a, rs_b, ss_b,
        Wl + 2 * WD, Wr + 2 * WD, bl + 2 * DIM, rp, xm1);

    out_kernel<<<N_NODES / 4, 256, 0, stream>>>(xm1, Wo, bo, out);
}

// Round 4
// 1137.137 us; speedup vs baseline: 2.3940x; 1.8994x over previous
//
#include <hip/hip_runtime.h>
#include <math.h>

#define N_NODES 100000
#define N_EDGES 1600000
#define DIM 128
#define NCLS 40

typedef unsigned short u16;
typedef unsigned int u32;
typedef __attribute__((ext_vector_type(8))) short bf16x8;
typedef __attribute__((ext_vector_type(4))) float f32x4;

union Frag { bf16x8 v; u16 u[8]; uint4 ui; };

__device__ __forceinline__ float b2f_lo(u32 u){ union{u32 i;float f;}c; c.i=u<<16; return c.f; }
__device__ __forceinline__ float b2f_hi(u32 u){ union{u32 i;float f;}c; c.i=u&0xffff0000u; return c.f; }
__device__ __forceinline__ u16 f2b(float f){ union{float f;u32 i;}c; c.f=f; u32 r=c.i+0x7fffu+((c.i>>16)&1u); return (u16)(r>>16); }

// ---------------- CSR build ----------------

__global__ void hist_kernel(const int* __restrict__ dst, int* __restrict__ cnt, int E) {
    int e = blockIdx.x * blockDim.x + threadIdx.x;
    if (e < E) atomicAdd(&cnt[dst[e]], 1);
}

__global__ void scan_blocks(const int* __restrict__ in, int* __restrict__ out,
                            int* __restrict__ bsums, int n) {
    __shared__ int s[256];
    int i = blockIdx.x * 256 + threadIdx.x;
    int v = (i < n) ? in[i] : 0;
    s[threadIdx.x] = v;
    __syncthreads();
    for (int d = 1; d < 256; d <<= 1) {
        int t = (threadIdx.x >= d) ? s[threadIdx.x - d] : 0;
        __syncthreads();
        s[threadIdx.x] += t;
        __syncthreads();
    }
    if (i < n) out[i] = s[threadIdx.x] - v;
    if (threadIdx.x == 255) bsums[blockIdx.x] = s[255];
}

__global__ void scan_small(int* data, int n) {
    __shared__ int s[512];
    int v = (threadIdx.x < n) ? data[threadIdx.x] : 0;
    s[threadIdx.x] = v;
    __syncthreads();
    for (int d = 1; d < 512; d <<= 1) {
        int t = (threadIdx.x >= d) ? s[threadIdx.x - d] : 0;
        __syncthreads();
        s[threadIdx.x] += t;
        __syncthreads();
    }
    if (threadIdx.x < n) data[threadIdx.x] = s[threadIdx.x] - v;
}

__global__ void add_offsets(int* __restrict__ rs, const int* __restrict__ bsums,
                            int n, int total) {
    int i = blockIdx.x * 256 + threadIdx.x;
    if (i < n) rs[i] += bsums[blockIdx.x];
    if (blockIdx.x == 0 && threadIdx.x == 0) rs[n] = total;
}

__global__ void scatter_kernel(const int* __restrict__ src, const int* __restrict__ dst,
                               const int* __restrict__ rs, int* __restrict__ cursor,
                               int* __restrict__ ss, const int* __restrict__ perm, int E) {
    int e = blockIdx.x * blockDim.x + threadIdx.x;
    if (e >= E) return;
    int d = dst[e];
    int p = atomicAdd(&cursor[d], 1);
    int s = src[e];
    if (perm) s = perm[s];
    ss[rs[d] + p] = s;
}

// xb = bf16(x); xm0 = bf16(r*x + (1-r)*x[perm])
__global__ void conv_mix(const float* __restrict__ x, const int* __restrict__ perm,
                         const float* __restrict__ rp, u16* __restrict__ xb,
                         u16* __restrict__ xm) {
    int i = blockIdx.x * 256 + threadIdx.x;
    int n = i >> 7, f = i & 127;
    float xv = x[i];
    float r = *rp;
    int p = perm[n];
    xb[i] = f2b(xv);
    xm[i] = f2b(r * xv + (1.f - r) * x[(size_t)p * DIM + f]);
}

// pack W[3][128][128] fp32 -> bf16 B-fragment order for mfma_f32_16x16x32_bf16:
// frag element (layer, c, t, lane l, j) = W[layer][t*32 + (l>>4)*8 + j][c*16 + (l&15)]
__global__ void pack_weights(const float* __restrict__ Wl, const float* __restrict__ Wr,
                             u16* __restrict__ WlP, u16* __restrict__ WrP) {
    int i = blockIdx.x * 256 + threadIdx.x;          // [0, 3*16384)
    int layer = i >> 14, idx = i & 16383;
    int j = idx & 7, l = (idx >> 3) & 63, t = (idx >> 9) & 3, c = idx >> 11;
    int k = t * 32 + ((l >> 4) << 3) + j;
    int col = (c << 4) + (l & 15);
    WlP[i] = f2b(Wl[layer * 16384 + k * DIM + col]);
    WrP[i] = f2b(Wr[layer * 16384 + k * DIM + col]);
}

// ---------------- gather into MFMA A-frag layout ----------------
// lane handles node m=lane&15, k-chunk q=lane>>4. Per edge: 4 independent 16B loads
// (one per 32-k slice). 16 nodes' edge streams run concurrently across the wave.

__device__ __forceinline__ void addv(float* a, uint4 v) {
    a[0] += b2f_lo(v.x); a[1] += b2f_hi(v.x);
    a[2] += b2f_lo(v.y); a[3] += b2f_hi(v.y);
    a[4] += b2f_lo(v.z); a[5] += b2f_hi(v.z);
    a[6] += b2f_lo(v.w); a[7] += b2f_hi(v.w);
}

__device__ __forceinline__ void gather_frags(const u16* __restrict__ src,
        const int* __restrict__ ss, int beg, int end, int q, Frag* f) {
    float acc[4][8];
    #pragma unroll
    for (int t = 0; t < 4; ++t)
        #pragma unroll
        for (int j = 0; j < 8; ++j) acc[t][j] = 0.f;
    const u16* sq = src + q * 8;
    #pragma unroll 2
    for (int e = beg; e < end; ++e) {
        int s = ss[e];
        const u16* rowp = sq + (size_t)s * DIM;
        uint4 v0 = *(const uint4*)(rowp);
        uint4 v1 = *(const uint4*)(rowp + 32);
        uint4 v2 = *(const uint4*)(rowp + 64);
        uint4 v3 = *(const uint4*)(rowp + 96);
        addv(acc[0], v0); addv(acc[1], v1); addv(acc[2], v2); addv(acc[3], v3);
    }
    float inv = (end > beg) ? 1.f / (float)(end - beg) : 0.f;
    #pragma unroll
    for (int t = 0; t < 4; ++t)
        #pragma unroll
        for (int j = 0; j < 8; ++j) f[t].u[j] = f2b(acc[t][j] * inv);
}

__device__ __forceinline__ void load_frags(const u16* __restrict__ row, int q, Frag* f) {
    const u16* p = row + q * 8;
    f[0].ui = *(const uint4*)(p);
    f[1].ui = *(const uint4*)(p + 32);
    f[2].ui = *(const uint4*)(p + 64);
    f[3].ui = *(const uint4*)(p + 96);
}

// ---------------- fused sage kernels: 1 wave = 16 nodes, zero LDS ----------------

// A = relu(agg_a@Wl + X@Wr + bl); stores agg (bf16) to Tout for reuse
__global__ __launch_bounds__(256) void sage_pre(
        const u16* __restrict__ src, const int* __restrict__ rs, const int* __restrict__ ss,
        const u16* __restrict__ WlP, const u16* __restrict__ WrP,
        const float* __restrict__ bl, u16* __restrict__ A, u16* __restrict__ Tout)
{
    const int lane = threadIdx.x & 63;
    const int wave = threadIdx.x >> 6;
    const int nb = blockIdx.x * 64 + wave * 16;
    const int m = lane & 15, q = lane >> 4;
    const int n = nb + m;
    const bool vld = n < N_NODES;
    const int nc = vld ? n : N_NODES - 1;

    Frag fT[4], fX[4];
    gather_frags(src, ss, rs[nc], rs[nc + 1], q, fT);
    if (vld) {
        u16* tp = Tout + (size_t)n * DIM + q * 8;
        *(uint4*)(tp)      = fT[0].ui;
        *(uint4*)(tp + 32) = fT[1].ui;
        *(uint4*)(tp + 64) = fT[2].ui;
        *(uint4*)(tp + 96) = fT[3].ui;
    }
    load_frags(src + (size_t)nc * DIM, q, fX);

    const int col = m;
    const int rowb = q * 4;
    for (int c = 0; c < 8; ++c) {
        f32x4 a = {0.f, 0.f, 0.f, 0.f};
        #pragma unroll
        for (int t = 0; t < 4; ++t) {
            Frag wl, wr;
            wl.ui = *(const uint4*)(WlP + ((c * 4 + t) * 64 + lane) * 8);
            wr.ui = *(const uint4*)(WrP + ((c * 4 + t) * 64 + lane) * 8);
            a = __builtin_amdgcn_mfma_f32_16x16x32_bf16(fT[t].v, wl.v, a, 0, 0, 0);
            a = __builtin_amdgcn_mfma_f32_16x16x32_bf16(fX[t].v, wr.v, a, 0, 0, 0);
        }
        float bias = bl[c * 16 + col];
        #pragma unroll
        for (int r2 = 0; r2 < 4; ++r2) {
            int nr = nb + rowb + r2;
            if (nr < N_NODES)
                A[(size_t)nr * DIM + c * 16 + col] = f2b(fmaxf(a[r2] + bias, 0.f));
        }
    }
}

// xm_new = r*relu(Ta@Wl+b+S) + (1-r)*relu(Tb@Wl+b+S), S = xm@Wr (computed once)
template<bool GATHER_A>
__global__ __launch_bounds__(256) void sage_main(
        const u16* __restrict__ src, const u16* __restrict__ Tpre,
        const u16* __restrict__ xm,
        const int* __restrict__ rs_a, const int* __restrict__ ss_a,
        const int* __restrict__ rs_b, const int* __restrict__ ss_b,
        const u16* __restrict__ WlP, const u16* __restrict__ WrP,
        const float* __restrict__ bl, const float* __restrict__ rp,
        u16* __restrict__ xout)
{
    const int lane = threadIdx.x & 63;
    const int wave = threadIdx.x >> 6;
    const int nb = blockIdx.x * 64 + wave * 16;
    const int m = lane & 15, q = lane >> 4;
    const int n = nb + m;
    const bool vld = n < N_NODES;
    const int nc = vld ? n : N_NODES - 1;

    Frag fA[4], fB[4], fX[4];
    if (GATHER_A)
        gather_frags(src, ss_a, rs_a[nc], rs_a[nc + 1], q, fA);
    else
        load_frags(Tpre + (size_t)nc * DIM, q, fA);
    gather_frags(src, ss_b, rs_b[nc], rs_b[nc + 1], q, fB);
    load_frags(xm + (size_t)nc * DIM, q, fX);
    float r = *rp;

    const int col = m;
    const int rowb = q * 4;
    for (int c = 0; c < 8; ++c) {
        f32x4 s = {0.f, 0.f, 0.f, 0.f};
        Frag wl[4];
        #pragma unroll
        for (int t = 0; t < 4; ++t) {
            Frag wr;
            wr.ui = *(const uint4*)(WrP + ((c * 4 + t) * 64 + lane) * 8);
            wl[t].ui = *(const uint4*)(WlP + ((c * 4 + t) * 64 + lane) * 8);
            s = __builtin_amdgcn_mfma_f32_16x16x32_bf16(fX[t].v, wr.v, s, 0, 0, 0);
        }
        f32x4 pa = s, pb = s;
        #pragma unroll
        for (int t = 0; t < 4; ++t)
            pa = __builtin_amdgcn_mfma_f32_16x16x32_bf16(fA[t].v, wl[t].v, pa, 0, 0, 0);
        #pragma unroll
        for (int t = 0; t < 4; ++t)
            pb = __builtin_amdgcn_mfma_f32_16x16x32_bf16(fB[t].v, wl[t].v, pb, 0, 0, 0);
        float bias = bl[c * 16 + col];
        #pragma unroll
        for (int r2 = 0; r2 < 4; ++r2) {
            int nr = nb + rowb + r2;
            if (nr < N_NODES) {
                float va = fmaxf(pa[r2] + bias, 0.f);
                float vb = fmaxf(pb[r2] + bias, 0.f);
                xout[(size_t)nr * DIM + c * 16 + col] = f2b(r * va + (1.f - r) * vb);
            }
        }
    }
}

// coalesced bf16 row -> fp32 LDS row (64 lanes x 2 feats)
__device__ __forceinline__ void load_row(const u16* __restrict__ row, int lane,
                                         float* __restrict__ ldsrow) {
    u32 v = *(const u32*)(row + lane * 2);
    ldsrow[lane * 2]     = b2f_lo(v);
    ldsrow[lane * 2 + 1] = b2f_hi(v);
}

// logits + log_softmax; 4 waves/block, one node per wave
__global__ __launch_bounds__(256) void out_kernel(const u16* __restrict__ xm,
        const float* __restrict__ Wo, const float* __restrict__ bo,
        float* __restrict__ out) {
    __shared__ float row[4][DIM];
    const int wave = threadIdx.x >> 6;
    const int lane = threadIdx.x & 63;
    const int n = blockIdx.x * 4 + wave;
    load_row(xm + (size_t)n * DIM, lane, row[wave]);
    float acc = -1e30f;
    if (lane < NCLS) {
        acc = bo[lane];
        #pragma unroll 4
        for (int k = 0; k < DIM; ++k) acc += row[wave][k] * Wo[k * NCLS + lane];
    }
    float mx = acc;
    for (int o = 32; o > 0; o >>= 1) mx = fmaxf(mx, __shfl_xor(mx, o, 64));
    float e = (lane < NCLS) ? expf(acc - mx) : 0.f;
    float sum = e;
    for (int o = 32; o > 0; o >>= 1) sum += __shfl_xor(sum, o, 64);
    if (lane < NCLS) out[(size_t)n * NCLS + lane] = acc - mx - logf(sum);
}

// ---------------- driver ----------------

extern "C" void kernel_launch(void* const* d_in, const int* in_sizes, int n_in,
                              void* d_out, int out_size, void* d_ws, size_t ws_size,
                              hipStream_t stream) {
    const float* x    = (const float*)d_in[0];
    const float* Wl   = (const float*)d_in[1];
    const float* bl   = (const float*)d_in[2];
    const float* Wr   = (const float*)d_in[3];
    const float* Wo   = (const float*)d_in[4];
    const float* bo   = (const float*)d_in[5];
    const float* rp   = (const float*)d_in[6];
    const int*   adj  = (const int*)d_in[7];
    const int*   adjb = (const int*)d_in[8];
    const int*   perm = (const int*)d_in[9];
    float* out = (float*)d_out;

    char* ws = (char*)d_ws;
    size_t off = 0;
    auto alloc = [&](size_t bytes) {
        char* p = ws + off;
        off += (bytes + 255) & ~(size_t)255;
        return p;
    };
    int* rs_a   = (int*)alloc((N_NODES + 1) * 4);
    int* rs_b   = (int*)alloc((N_NODES + 1) * 4);
    int* ss_a   = (int*)alloc((size_t)N_EDGES * 4);
    int* ss_b   = (int*)alloc((size_t)N_EDGES * 4);
    int* cursor = (int*)alloc((size_t)N_NODES * 4);
    int* bsums  = (int*)alloc(512 * 4);
    u16* WlP    = (u16*)alloc(3 * 16384 * 2);
    u16* WrP    = (u16*)alloc(3 * 16384 * 2);
    const size_t FB = (size_t)N_NODES * DIM * 2;   // bf16 feature buffer (25.6 MB)
    u16* xb  = (u16*)alloc(FB);
    u16* xm0 = (u16*)alloc(FB);
    u16* A1  = (u16*)alloc(FB);
    u16* A2  = (u16*)alloc(FB);
    u16* T0  = (u16*)alloc(FB);    // aliased as xm1 (row-for-row safe)
    u16* T1  = (u16*)alloc(FB);
    u16* xm1 = T0;

    const int nbE = (N_EDGES + 255) / 256;
    const int nbN = (N_NODES + 255) / 256;

    // CSR for adj
    hipMemsetAsync(cursor, 0, (size_t)N_NODES * 4, stream);
    hist_kernel<<<nbE, 256, 0, stream>>>(adj + N_EDGES, cursor, N_EDGES);
    scan_blocks<<<nbN, 256, 0, stream>>>(cursor, rs_a, bsums, N_NODES);
    scan_small<<<1, 512, 0, stream>>>(bsums, nbN);
    add_offsets<<<nbN, 256, 0, stream>>>(rs_a, bsums, N_NODES, N_EDGES);
    hipMemsetAsync(cursor, 0, (size_t)N_NODES * 4, stream);
    scatter_kernel<<<nbE, 256, 0, stream>>>(adj, adj + N_EDGES, rs_a, cursor, ss_a,
                                            nullptr, N_EDGES);

    // CSR for adj_b (perm folded into stored sources)
    hipMemsetAsync(cursor, 0, (size_t)N_NODES * 4, stream);
    hist_kernel<<<nbE, 256, 0, stream>>>(adjb + N_EDGES, cursor, N_EDGES);
    scan_blocks<<<nbN, 256, 0, stream>>>(cursor, rs_b, bsums, N_NODES);
    scan_small<<<1, 512, 0, stream>>>(bsums, nbN);
    add_offsets<<<nbN, 256, 0, stream>>>(rs_b, bsums, N_NODES, N_EDGES);
    hipMemsetAsync(cursor, 0, (size_t)N_NODES * 4, stream);
    scatter_kernel<<<nbE, 256, 0, stream>>>(adjb, adjb + N_EDGES, rs_b, cursor, ss_b,
                                            perm, N_EDGES);

    // weight packing + input conversion/mix
    pack_weights<<<192, 256, 0, stream>>>(Wl, Wr, WlP, WrP);
    conv_mix<<<(N_NODES * DIM) / 256, 256, 0, stream>>>(x, perm, rp, xb, xm0);

    const int WP = 16384;                 // packed per-layer weight stride (u16)
    const int nbS = (N_NODES + 63) / 64;  // 1563 blocks, 64 nodes each

    // pre passes (save aggregations T0 = agg_a(xb), T1 = agg_a(A1))
    sage_pre<<<nbS, 256, 0, stream>>>(xb, rs_a, ss_a, WlP, WrP, bl, A1, T0);
    sage_pre<<<nbS, 256, 0, stream>>>(A1, rs_a, ss_a, WlP + WP, WrP + WP,
                                      bl + DIM, A2, T1);

    // main layers: 0/1 reuse T0/T1; layer 2 gathers both branches
    sage_main<false><<<nbS, 256, 0, stream>>>(xb, T0, xm0, rs_a, ss_a, rs_b, ss_b,
        WlP, WrP, bl, rp, xm1);
    sage_main<false><<<nbS, 256, 0, stream>>>(A1, T1, xm1, rs_a, ss_a, rs_b, ss_b,
        WlP + WP, WrP + WP, bl + DIM, rp, xm0);
    sage_main<true><<<nbS, 256, 0, stream>>>(A2, nullptr, xm0, rs_a, ss_a, rs_b, ss_b,
        WlP + 2 * WP, WrP + 2 * WP, bl + 2 * DIM, rp, xm1);

    out_kernel<<<N_NODES / 4, 256, 0, stream>>>(xm1, Wo, bo, out);
}

// Round 5
// 1065.922 us; speedup vs baseline: 2.5540x; 1.0668x over previous
//
#include <hip/hip_runtime.h>
#include <math.h>

#define N_NODES 100000
#define N_EDGES 1600000
#define DIM 128
#define NCLS 40

typedef unsigned short u16;
typedef unsigned int u32;
typedef unsigned char u8;
typedef __attribute__((ext_vector_type(8))) short bf16x8;
typedef __attribute__((ext_vector_type(4))) float f32x4;
typedef __attribute__((ext_vector_type(2))) float f32x2;

union Frag { bf16x8 v; u16 u[8]; uint4 ui; };

__device__ __forceinline__ float b2f_lo(u32 u){ union{u32 i;float f;}c; c.i=u<<16; return c.f; }
__device__ __forceinline__ float b2f_hi(u32 u){ union{u32 i;float f;}c; c.i=u&0xffff0000u; return c.f; }
__device__ __forceinline__ u16 f2b(float f){ union{float f;u32 i;}c; c.f=f; u32 r=c.i+0x7fffu+((c.i>>16)&1u); return (u16)(r>>16); }

// fp8 e4m3 (OCP) pack/unpack via HW converts
__device__ __forceinline__ u32 pack4_fp8(float a, float b, float c, float d) {
    u32 v = 0;
    v = __builtin_amdgcn_cvt_pk_fp8_f32(a, b, v, false);
    v = __builtin_amdgcn_cvt_pk_fp8_f32(c, d, v, true);
    return v;
}
__device__ __forceinline__ void addq(float* a, u32 w) {
    f32x2 p0 = __builtin_amdgcn_cvt_pk_f32_fp8(w, false);
    f32x2 p1 = __builtin_amdgcn_cvt_pk_f32_fp8(w, true);
    a[0] += p0.x; a[1] += p0.y; a[2] += p1.x; a[3] += p1.y;
}

// ---------------- CSR build ----------------

__global__ void hist_kernel(const int* __restrict__ dst, int* __restrict__ cnt, int E) {
    int e = blockIdx.x * blockDim.x + threadIdx.x;
    if (e < E) atomicAdd(&cnt[dst[e]], 1);
}

__global__ void scan_blocks(const int* __restrict__ in, int* __restrict__ out,
                            int* __restrict__ bsums, int n) {
    __shared__ int s[256];
    int i = blockIdx.x * 256 + threadIdx.x;
    int v = (i < n) ? in[i] : 0;
    s[threadIdx.x] = v;
    __syncthreads();
    for (int d = 1; d < 256; d <<= 1) {
        int t = (threadIdx.x >= d) ? s[threadIdx.x - d] : 0;
        __syncthreads();
        s[threadIdx.x] += t;
        __syncthreads();
    }
    if (i < n) out[i] = s[threadIdx.x] - v;
    if (threadIdx.x == 255) bsums[blockIdx.x] = s[255];
}

__global__ void scan_small(int* data, int n) {
    __shared__ int s[512];
    int v = (threadIdx.x < n) ? data[threadIdx.x] : 0;
    s[threadIdx.x] = v;
    __syncthreads();
    for (int d = 1; d < 512; d <<= 1) {
        int t = (threadIdx.x >= d) ? s[threadIdx.x - d] : 0;
        __syncthreads();
        s[threadIdx.x] += t;
        __syncthreads();
    }
    if (threadIdx.x < n) data[threadIdx.x] = s[threadIdx.x] - v;
}

__global__ void add_offsets(int* __restrict__ rs, const int* __restrict__ bsums,
                            int n, int total) {
    int i = blockIdx.x * 256 + threadIdx.x;
    if (i < n) rs[i] += bsums[blockIdx.x];
    if (blockIdx.x == 0 && threadIdx.x == 0) rs[n] = total;
}

__global__ void scatter_kernel(const int* __restrict__ src, const int* __restrict__ dst,
                               const int* __restrict__ rs, int* __restrict__ cursor,
                               int* __restrict__ ss, const int* __restrict__ perm, int E) {
    int e = blockIdx.x * blockDim.x + threadIdx.x;
    if (e >= E) return;
    int d = dst[e];
    int p = atomicAdd(&cursor[d], 1);
    int s = src[e];
    if (perm) s = perm[s];
    ss[rs[d] + p] = s;
}

// xb = bf16(x); xq = fp8(x); xm0 = bf16(r*x + (1-r)*x[perm])  — 4 elems/thread
__global__ void conv_mix(const float* __restrict__ x, const int* __restrict__ perm,
                         const float* __restrict__ rp, u16* __restrict__ xb,
                         u16* __restrict__ xm, u8* __restrict__ xq) {
    int i = (blockIdx.x * 256 + threadIdx.x) * 4;
    int n = i >> 7, f = i & 127;
    float r = *rp;
    int p = perm[n];
    float4 xv = *(const float4*)(x + i);
    float4 pv = *(const float4*)(x + (size_t)p * DIM + f);
    ushort4 b, m;
    b.x = f2b(xv.x); b.y = f2b(xv.y); b.z = f2b(xv.z); b.w = f2b(xv.w);
    m.x = f2b(r * xv.x + (1.f - r) * pv.x);
    m.y = f2b(r * xv.y + (1.f - r) * pv.y);
    m.z = f2b(r * xv.z + (1.f - r) * pv.z);
    m.w = f2b(r * xv.w + (1.f - r) * pv.w);
    *(ushort4*)(xb + i) = b;
    *(ushort4*)(xm + i) = m;
    *(u32*)(xq + i) = pack4_fp8(xv.x, xv.y, xv.z, xv.w);
}

// pack W[3][128][128] fp32 -> bf16 B-fragment order for mfma_f32_16x16x32_bf16:
// frag element (layer, c, t, lane l, j) = W[layer][t*32 + (l>>4)*8 + j][c*16 + (l&15)]
__global__ void pack_weights(const float* __restrict__ Wl, const float* __restrict__ Wr,
                             u16* __restrict__ WlP, u16* __restrict__ WrP) {
    int i = blockIdx.x * 256 + threadIdx.x;          // [0, 3*16384)
    int layer = i >> 14, idx = i & 16383;
    int j = idx & 7, l = (idx >> 3) & 63, t = (idx >> 9) & 3, c = idx >> 11;
    int k = t * 32 + ((l >> 4) << 3) + j;
    int col = (c << 4) + (l & 15);
    WlP[i] = f2b(Wl[layer * 16384 + k * DIM + col]);
    WrP[i] = f2b(Wr[layer * 16384 + k * DIM + col]);
}

// ---------------- fp8 gather into MFMA A-frag layout ----------------
// lane (m=lane&15, q=lane>>4): per edge 4x 8B loads (fp8 row = 128B).
// 16 nodes' edge streams run concurrently across the wave.

__device__ __forceinline__ void gather_frags_q(const u8* __restrict__ src,
        const int* __restrict__ ss, int beg, int end, int q, Frag* f) {
    float acc[4][8];
    #pragma unroll
    for (int t = 0; t < 4; ++t)
        #pragma unroll
        for (int j = 0; j < 8; ++j) acc[t][j] = 0.f;
    const u8* sq = src + q * 8;
    #pragma unroll 4
    for (int e = beg; e < end; ++e) {
        int s = ss[e];
        const u8* rowp = sq + (size_t)s * DIM;
        uint2 v0 = *(const uint2*)(rowp);
        uint2 v1 = *(const uint2*)(rowp + 32);
        uint2 v2 = *(const uint2*)(rowp + 64);
        uint2 v3 = *(const uint2*)(rowp + 96);
        addq(acc[0], v0.x); addq(acc[0] + 4, v0.y);
        addq(acc[1], v1.x); addq(acc[1] + 4, v1.y);
        addq(acc[2], v2.x); addq(acc[2] + 4, v2.y);
        addq(acc[3], v3.x); addq(acc[3] + 4, v3.y);
    }
    float inv = (end > beg) ? 1.f / (float)(end - beg) : 0.f;
    #pragma unroll
    for (int t = 0; t < 4; ++t)
        #pragma unroll
        for (int j = 0; j < 8; ++j) f[t].u[j] = f2b(acc[t][j] * inv);
}

// bf16 direct row -> A-frag
__device__ __forceinline__ void load_frags(const u16* __restrict__ row, int q, Frag* f) {
    const u16* p = row + q * 8;
    f[0].ui = *(const uint4*)(p);
    f[1].ui = *(const uint4*)(p + 32);
    f[2].ui = *(const uint4*)(p + 64);
    f[3].ui = *(const uint4*)(p + 96);
}

// ---------------- fused sage kernels: 1 wave = 16 nodes, zero LDS ----------------

// A = relu(agg_a@Wl + X@Wr + bl); writes agg (bf16) to Tout; A as bf16 (optional) + fp8
__global__ __launch_bounds__(256) void sage_pre(
        const u8* __restrict__ srcq, const u16* __restrict__ src,
        const int* __restrict__ rs, const int* __restrict__ ss,
        const u16* __restrict__ WlP, const u16* __restrict__ WrP,
        const float* __restrict__ bl, u16* __restrict__ A, u8* __restrict__ Aq,
        u16* __restrict__ Tout)
{
    const int lane = threadIdx.x & 63;
    const int wave = threadIdx.x >> 6;
    const int nb = blockIdx.x * 64 + wave * 16;
    const int m = lane & 15, q = lane >> 4;
    const int n = nb + m;
    const bool vld = n < N_NODES;
    const int nc = vld ? n : N_NODES - 1;

    Frag fT[4], fX[4];
    gather_frags_q(srcq, ss, rs[nc], rs[nc + 1], q, fT);
    if (vld) {
        u16* tp = Tout + (size_t)n * DIM + q * 8;
        *(uint4*)(tp)      = fT[0].ui;
        *(uint4*)(tp + 32) = fT[1].ui;
        *(uint4*)(tp + 64) = fT[2].ui;
        *(uint4*)(tp + 96) = fT[3].ui;
    }
    load_frags(src + (size_t)nc * DIM, q, fX);

    const int col = m;
    const int rowb = q * 4;
    for (int c = 0; c < 8; ++c) {
        f32x4 a = {0.f, 0.f, 0.f, 0.f};
        #pragma unroll
        for (int t = 0; t < 4; ++t) {
            Frag wl, wr;
            wl.ui = *(const uint4*)(WlP + ((c * 4 + t) * 64 + lane) * 8);
            wr.ui = *(const uint4*)(WrP + ((c * 4 + t) * 64 + lane) * 8);
            a = __builtin_amdgcn_mfma_f32_16x16x32_bf16(fT[t].v, wl.v, a, 0, 0, 0);
            a = __builtin_amdgcn_mfma_f32_16x16x32_bf16(fX[t].v, wr.v, a, 0, 0, 0);
        }
        float bias = bl[c * 16 + col];
        #pragma unroll
        for (int r2 = 0; r2 < 4; ++r2) {
            int nr = nb + rowb + r2;
            if (nr < N_NODES) {
                float v = fmaxf(a[r2] + bias, 0.f);
                if (A) A[(size_t)nr * DIM + c * 16 + col] = f2b(v);
                u32 q8 = 0;
                q8 = __builtin_amdgcn_cvt_pk_fp8_f32(v, v, q8, false);
                Aq[(size_t)nr * DIM + c * 16 + col] = (u8)(q8 & 0xff);
            }
        }
    }
}

// xm_new = r*relu(Ta@Wl+b+S) + (1-r)*relu(Tb@Wl+b+S), S = xm@Wr (computed once)
template<bool GATHER_A>
__global__ __launch_bounds__(256) void sage_main(
        const u8* __restrict__ srcq, const u16* __restrict__ Tpre,
        const u16* __restrict__ xm,
        const int* __restrict__ rs_a, const int* __restrict__ ss_a,
        const int* __restrict__ rs_b, const int* __restrict__ ss_b,
        const u16* __restrict__ WlP, const u16* __restrict__ WrP,
        const float* __restrict__ bl, const float* __restrict__ rp,
        u16* __restrict__ xout)
{
    const int lane = threadIdx.x & 63;
    const int wave = threadIdx.x >> 6;
    const int nb = blockIdx.x * 64 + wave * 16;
    const int m = lane & 15, q = lane >> 4;
    const int n = nb + m;
    const bool vld = n < N_NODES;
    const int nc = vld ? n : N_NODES - 1;

    Frag fA[4], fB[4], fX[4];
    if (GATHER_A)
        gather_frags_q(srcq, ss_a, rs_a[nc], rs_a[nc + 1], q, fA);
    else
        load_frags(Tpre + (size_t)nc * DIM, q, fA);
    gather_frags_q(srcq, ss_b, rs_b[nc], rs_b[nc + 1], q, fB);
    load_frags(xm + (size_t)nc * DIM, q, fX);
    float r = *rp;

    const int col = m;
    const int rowb = q * 4;
    for (int c = 0; c < 8; ++c) {
        f32x4 s = {0.f, 0.f, 0.f, 0.f};
        Frag wl[4];
        #pragma unroll
        for (int t = 0; t < 4; ++t) {
            Frag wr;
            wr.ui = *(const uint4*)(WrP + ((c * 4 + t) * 64 + lane) * 8);
            wl[t].ui = *(const uint4*)(WlP + ((c * 4 + t) * 64 + lane) * 8);
            s = __builtin_amdgcn_mfma_f32_16x16x32_bf16(fX[t].v, wr.v, s, 0, 0, 0);
        }
        f32x4 pa = s, pb = s;
        #pragma unroll
        for (int t = 0; t < 4; ++t)
            pa = __builtin_amdgcn_mfma_f32_16x16x32_bf16(fA[t].v, wl[t].v, pa, 0, 0, 0);
        #pragma unroll
        for (int t = 0; t < 4; ++t)
            pb = __builtin_amdgcn_mfma_f32_16x16x32_bf16(fB[t].v, wl[t].v, pb, 0, 0, 0);
        float bias = bl[c * 16 + col];
        #pragma unroll
        for (int r2 = 0; r2 < 4; ++r2) {
            int nr = nb + rowb + r2;
            if (nr < N_NODES) {
                float va = fmaxf(pa[r2] + bias, 0.f);
                float vb = fmaxf(pb[r2] + bias, 0.f);
                xout[(size_t)nr * DIM + c * 16 + col] = f2b(r * va + (1.f - r) * vb);
            }
        }
    }
}

// coalesced bf16 row -> fp32 LDS row (64 lanes x 2 feats)
__device__ __forceinline__ void load_row(const u16* __restrict__ row, int lane,
                                         float* __restrict__ ldsrow) {
    u32 v = *(const u32*)(row + lane * 2);
    ldsrow[lane * 2]     = b2f_lo(v);
    ldsrow[lane * 2 + 1] = b2f_hi(v);
}

// logits + log_softmax; 4 waves/block, one node per wave
__global__ __launch_bounds__(256) void out_kernel(const u16* __restrict__ xm,
        const float* __restrict__ Wo, const float* __restrict__ bo,
        float* __restrict__ out) {
    __shared__ float row[4][DIM];
    const int wave = threadIdx.x >> 6;
    const int lane = threadIdx.x & 63;
    const int n = blockIdx.x * 4 + wave;
    load_row(xm + (size_t)n * DIM, lane, row[wave]);
    float acc = -1e30f;
    if (lane < NCLS) {
        acc = bo[lane];
        #pragma unroll 4
        for (int k = 0; k < DIM; ++k) acc += row[wave][k] * Wo[k * NCLS + lane];
    }
    float mx = acc;
    for (int o = 32; o > 0; o >>= 1) mx = fmaxf(mx, __shfl_xor(mx, o, 64));
    float e = (lane < NCLS) ? expf(acc - mx) : 0.f;
    float sum = e;
    for (int o = 32; o > 0; o >>= 1) sum += __shfl_xor(sum, o, 64);
    if (lane < NCLS) out[(size_t)n * NCLS + lane] = acc - mx - logf(sum);
}

// ---------------- driver ----------------

extern "C" void kernel_launch(void* const* d_in, const int* in_sizes, int n_in,
                              void* d_out, int out_size, void* d_ws, size_t ws_size,
                              hipStream_t stream) {
    const float* x    = (const float*)d_in[0];
    const float* Wl   = (const float*)d_in[1];
    const float* bl   = (const float*)d_in[2];
    const float* Wr   = (const float*)d_in[3];
    const float* Wo   = (const float*)d_in[4];
    const float* bo   = (const float*)d_in[5];
    const float* rp   = (const float*)d_in[6];
    const int*   adj  = (const int*)d_in[7];
    const int*   adjb = (const int*)d_in[8];
    const int*   perm = (const int*)d_in[9];
    float* out = (float*)d_out;

    char* ws = (char*)d_ws;
    size_t off = 0;
    auto alloc = [&](size_t bytes) {
        char* p = ws + off;
        off += (bytes + 255) & ~(size_t)255;
        return p;
    };
    int* rs_a   = (int*)alloc((N_NODES + 1) * 4);
    int* rs_b   = (int*)alloc((N_NODES + 1) * 4);
    int* ss_a   = (int*)alloc((size_t)N_EDGES * 4);
    int* ss_b   = (int*)alloc((size_t)N_EDGES * 4);
    int* cursor = (int*)alloc((size_t)N_NODES * 4);
    int* bsums  = (int*)alloc(512 * 4);
    u16* WlP    = (u16*)alloc(3 * 16384 * 2);
    u16* WrP    = (u16*)alloc(3 * 16384 * 2);
    const size_t FB = (size_t)N_NODES * DIM * 2;   // bf16 feature buffer (25.6 MB)
    const size_t QB = (size_t)N_NODES * DIM;       // fp8  feature buffer (12.8 MB)
    u16* xb  = (u16*)alloc(FB);    // bf16 x; front 12.8 MB re-used as A2q later
    u16* xm0 = (u16*)alloc(FB);
    u16* A1  = (u16*)alloc(FB);
    u16* T0  = (u16*)alloc(FB);    // aliased as xm1 (row-for-row safe)
    u16* T1  = (u16*)alloc(FB);
    u8*  xq  = (u8*)alloc(QB);
    u8*  A1q = (u8*)alloc(QB);
    u16* xm1 = T0;
    u8*  A2q = (u8*)xb;            // alias: xb's last read (pre1 fX) precedes pre2's write
    // total ws use ~167 MB

    const int nbE = (N_EDGES + 255) / 256;
    const int nbN = (N_NODES + 255) / 256;

    // CSR for adj
    hipMemsetAsync(cursor, 0, (size_t)N_NODES * 4, stream);
    hist_kernel<<<nbE, 256, 0, stream>>>(adj + N_EDGES, cursor, N_EDGES);
    scan_blocks<<<nbN, 256, 0, stream>>>(cursor, rs_a, bsums, N_NODES);
    scan_small<<<1, 512, 0, stream>>>(bsums, nbN);
    add_offsets<<<nbN, 256, 0, stream>>>(rs_a, bsums, N_NODES, N_EDGES);
    hipMemsetAsync(cursor, 0, (size_t)N_NODES * 4, stream);
    scatter_kernel<<<nbE, 256, 0, stream>>>(adj, adj + N_EDGES, rs_a, cursor, ss_a,
                                            nullptr, N_EDGES);

    // CSR for adj_b (perm folded into stored sources)
    hipMemsetAsync(cursor, 0, (size_t)N_NODES * 4, stream);
    hist_kernel<<<nbE, 256, 0, stream>>>(adjb + N_EDGES, cursor, N_EDGES);
    scan_blocks<<<nbN, 256, 0, stream>>>(cursor, rs_b, bsums, N_NODES);
    scan_small<<<1, 512, 0, stream>>>(bsums, nbN);
    add_offsets<<<nbN, 256, 0, stream>>>(rs_b, bsums, N_NODES, N_EDGES);
    hipMemsetAsync(cursor, 0, (size_t)N_NODES * 4, stream);
    scatter_kernel<<<nbE, 256, 0, stream>>>(adjb, adjb + N_EDGES, rs_b, cursor, ss_b,
                                            perm, N_EDGES);

    // weight packing + input conversion/mix
    pack_weights<<<192, 256, 0, stream>>>(Wl, Wr, WlP, WrP);
    conv_mix<<<(N_NODES * DIM) / 1024, 256, 0, stream>>>(x, perm, rp, xb, xm0, xq);

    const int WP = 16384;                 // packed per-layer weight stride (u16)
    const int nbS = (N_NODES + 63) / 64;  // 1563 blocks, 64 nodes each

    // pre passes (save aggregations T0 = agg_a(x), T1 = agg_a(A1))
    sage_pre<<<nbS, 256, 0, stream>>>(xq, xb, rs_a, ss_a, WlP, WrP, bl,
                                      A1, A1q, T0);
    sage_pre<<<nbS, 256, 0, stream>>>(A1q, A1, rs_a, ss_a, WlP + WP, WrP + WP,
                                      bl + DIM, nullptr, A2q, T1);

    // main layers: 0/1 reuse T0/T1; layer 2 gathers both branches (fp8)
    sage_main<false><<<nbS, 256, 0, stream>>>(xq, T0, xm0, rs_a, ss_a, rs_b, ss_b,
        WlP, WrP, bl, rp, xm1);
    sage_main<false><<<nbS, 256, 0, stream>>>(A1q, T1, xm1, rs_a, ss_a, rs_b, ss_b,
        WlP + WP, WrP + WP, bl + DIM, rp, xm0);
    sage_main<true><<<nbS, 256, 0, stream>>>(A2q, nullptr, xm0, rs_a, ss_a, rs_b, ss_b,
        WlP + 2 * WP, WrP + 2 * WP, bl + 2 * DIM, rp, xm1);

    out_kernel<<<N_NODES / 4, 256, 0, stream>>>(xm1, Wo, bo, out);
}

// Round 6
// 1038.252 us; speedup vs baseline: 2.6220x; 1.0267x over previous
//
#include <hip/hip_runtime.h>
#include <math.h>

#define N_NODES 100000
#define N_EDGES 1600000
#define DIM 128
#define NCLS 40

typedef unsigned short u16;
typedef unsigned int u32;
typedef unsigned char u8;
typedef __attribute__((ext_vector_type(8))) short bf16x8;
typedef __attribute__((ext_vector_type(4))) float f32x4;
typedef __attribute__((ext_vector_type(2))) float f32x2;

union Frag { bf16x8 v; u16 u[8]; uint4 ui; };

__device__ __forceinline__ float b2f_lo(u32 u){ union{u32 i;float f;}c; c.i=u<<16; return c.f; }
__device__ __forceinline__ float b2f_hi(u32 u){ union{u32 i;float f;}c; c.i=u&0xffff0000u; return c.f; }
__device__ __forceinline__ u16 f2b(float f){ union{float f;u32 i;}c; c.f=f; u32 r=c.i+0x7fffu+((c.i>>16)&1u); return (u16)(r>>16); }

// fp8 e4m3 (OCP) pack/unpack via HW converts
__device__ __forceinline__ u32 pack4_fp8(float a, float b, float c, float d) {
    u32 v = 0;
    v = __builtin_amdgcn_cvt_pk_fp8_f32(a, b, v, false);
    v = __builtin_amdgcn_cvt_pk_fp8_f32(c, d, v, true);
    return v;
}
__device__ __forceinline__ void addq(float* a, u32 w) {
    f32x2 p0 = __builtin_amdgcn_cvt_pk_f32_fp8(w, false);
    f32x2 p1 = __builtin_amdgcn_cvt_pk_f32_fp8(w, true);
    a[0] += p0.x; a[1] += p0.y; a[2] += p1.x; a[3] += p1.y;
}

// ---------------- CSR build (both graphs per kernel) ----------------

__global__ void hist2(const int* __restrict__ dA, const int* __restrict__ dB,
                      int* __restrict__ cA, int* __restrict__ cB, int E) {
    int e = blockIdx.x * blockDim.x + threadIdx.x;
    if (e < E) atomicAdd(&cA[dA[e]], 1);
    else { e -= E; if (e < E) atomicAdd(&cB[dB[e]], 1); }
}

__global__ void scan_blocks2(const int* __restrict__ inA, const int* __restrict__ inB,
                             int* __restrict__ outA, int* __restrict__ outB,
                             int* __restrict__ bsA, int* __restrict__ bsB,
                             int n, int nb) {
    __shared__ int s[256];
    int half = blockIdx.x >= nb, b = blockIdx.x - half * nb;
    const int* in = half ? inB : inA;
    int* out = half ? outB : outA;
    int* bs  = half ? bsB  : bsA;
    int i = b * 256 + threadIdx.x;
    int v = (i < n) ? in[i] : 0;
    s[threadIdx.x] = v;
    __syncthreads();
    for (int d = 1; d < 256; d <<= 1) {
        int t = (threadIdx.x >= d) ? s[threadIdx.x - d] : 0;
        __syncthreads();
        s[threadIdx.x] += t;
        __syncthreads();
    }
    if (i < n) out[i] = s[threadIdx.x] - v;
    if (threadIdx.x == 255) bs[b] = s[255];
}

__global__ void scan_small2(int* __restrict__ bsA, int* __restrict__ bsB, int n) {
    __shared__ int s[512];
    int* data = blockIdx.x ? bsB : bsA;
    int v = (threadIdx.x < n) ? data[threadIdx.x] : 0;
    s[threadIdx.x] = v;
    __syncthreads();
    for (int d = 1; d < 512; d <<= 1) {
        int t = (threadIdx.x >= d) ? s[threadIdx.x - d] : 0;
        __syncthreads();
        s[threadIdx.x] += t;
        __syncthreads();
    }
    if (threadIdx.x < n) data[threadIdx.x] = s[threadIdx.x] - v;
}

__global__ void add_offsets2(int* __restrict__ rsA, int* __restrict__ rsB,
                             const int* __restrict__ bsA, const int* __restrict__ bsB,
                             int n, int nb, int total) {
    int half = blockIdx.x >= nb, b = blockIdx.x - half * nb;
    int* rs = half ? rsB : rsA;
    const int* bs = half ? bsB : bsA;
    int i = b * 256 + threadIdx.x;
    if (i < n) rs[i] += bs[b];
    if (b == 0 && threadIdx.x == 0) rs[n] = total;
}

__global__ void scatter2(const int* __restrict__ adjA, const int* __restrict__ adjB,
                         const int* __restrict__ rsA, const int* __restrict__ rsB,
                         int* __restrict__ curA, int* __restrict__ curB,
                         int* __restrict__ ssA, int* __restrict__ ssB,
                         const int* __restrict__ perm, int E) {
    int i = blockIdx.x * blockDim.x + threadIdx.x;
    if (i < E) {
        int d = adjA[E + i];
        int p = atomicAdd(&curA[d], 1);
        ssA[rsA[d] + p] = adjA[i];
    } else {
        i -= E;
        if (i < E) {
            int d = adjB[E + i];
            int p = atomicAdd(&curB[d], 1);
            ssB[rsB[d] + p] = perm[adjB[i]];
        }
    }
}

// xb = bf16(x); xq = fp8(x); xm0 = bf16(r*x + (1-r)*x[perm])  — 4 elems/thread
__global__ void conv_mix(const float* __restrict__ x, const int* __restrict__ perm,
                         const float* __restrict__ rp, u16* __restrict__ xb,
                         u16* __restrict__ xm, u8* __restrict__ xq) {
    int i = (blockIdx.x * 256 + threadIdx.x) * 4;
    int n = i >> 7, f = i & 127;
    float r = *rp;
    int p = perm[n];
    float4 xv = *(const float4*)(x + i);
    float4 pv = *(const float4*)(x + (size_t)p * DIM + f);
    ushort4 b, m;
    b.x = f2b(xv.x); b.y = f2b(xv.y); b.z = f2b(xv.z); b.w = f2b(xv.w);
    m.x = f2b(r * xv.x + (1.f - r) * pv.x);
    m.y = f2b(r * xv.y + (1.f - r) * pv.y);
    m.z = f2b(r * xv.z + (1.f - r) * pv.z);
    m.w = f2b(r * xv.w + (1.f - r) * pv.w);
    *(ushort4*)(xb + i) = b;
    *(ushort4*)(xm + i) = m;
    *(u32*)(xq + i) = pack4_fp8(xv.x, xv.y, xv.z, xv.w);
}

// pack W fp32 -> bf16 B-fragment order, k-PERMUTED mapping:
// frag (c, t, lane l (q=l>>4, n=l&15), j) holds W[k][c*16+n],
//   k = (t>>1)*64 + q*16 + (t&1)*8 + j
// (bijective over k=0..127; matches the 2x16B-per-edge gather layout)
__global__ void pack_weights(const float* __restrict__ Wl, const float* __restrict__ Wr,
                             u16* __restrict__ WlP, u16* __restrict__ WrP) {
    int i = blockIdx.x * 256 + threadIdx.x;          // [0, 3*16384)
    int layer = i >> 14, idx = i & 16383;
    int j = idx & 7, l = (idx >> 3) & 63, t = (idx >> 9) & 3, c = idx >> 11;
    int k = ((t >> 1) << 6) + (((l >> 4)) << 4) + ((t & 1) << 3) + j;
    int col = (c << 4) + (l & 15);
    WlP[i] = f2b(Wl[layer * 16384 + k * DIM + col]);
    WrP[i] = f2b(Wr[layer * 16384 + k * DIM + col]);
}

// ---------------- fp8 gather, 2x16B per edge ----------------
// lane (m=lane&15, q=lane>>4): per edge, 2 contiguous uint4 loads:
//   bytes [q*16, q*16+16) and [64+q*16, 64+q*16+16) of the 128B fp8 row.
// acc[t*8+j] ↔ logical k = (t>=2)*64 + q*16 + (t&1)*8 + j  (matches pack_weights)

__device__ __forceinline__ void gather_frags_q(const u8* __restrict__ src,
        const int* __restrict__ ss, int beg, int end, int q, Frag* f) {
    float acc[32];
    #pragma unroll
    for (int j = 0; j < 32; ++j) acc[j] = 0.f;
    const u8* s0 = src + q * 16;
    const u8* s1 = src + 64 + q * 16;
    #pragma unroll 4
    for (int e = beg; e < end; ++e) {
        int s = ss[e];
        uint4 v0 = *(const uint4*)(s0 + (size_t)s * DIM);
        uint4 v1 = *(const uint4*)(s1 + (size_t)s * DIM);
        addq(acc +  0, v0.x); addq(acc +  4, v0.y);
        addq(acc +  8, v0.z); addq(acc + 12, v0.w);
        addq(acc + 16, v1.x); addq(acc + 20, v1.y);
        addq(acc + 24, v1.z); addq(acc + 28, v1.w);
    }
    float inv = (end > beg) ? 1.f / (float)(end - beg) : 0.f;
    #pragma unroll
    for (int t = 0; t < 4; ++t)
        #pragma unroll
        for (int j = 0; j < 8; ++j) f[t].u[j] = f2b(acc[t * 8 + j] * inv);
}

// bf16 direct row -> frags, same k-permuted mapping (2x32B per lane)
__device__ __forceinline__ void load_frags(const u16* __restrict__ row, int q, Frag* f) {
    const u16* p = row + q * 16;
    f[0].ui = *(const uint4*)(p);
    f[1].ui = *(const uint4*)(p + 8);
    f[2].ui = *(const uint4*)(p + 64);
    f[3].ui = *(const uint4*)(p + 72);
}

// ---------------- fused sage kernels: 1 wave = 16 nodes, zero LDS ----------------

// A = relu(agg_a@Wl + X@Wr + bl); writes agg (bf16, permuted layout) to Tout;
// A stored row-major as bf16 (optional) + fp8
__global__ __launch_bounds__(256) void sage_pre(
        const u8* __restrict__ srcq, const u16* __restrict__ src,
        const int* __restrict__ rs, const int* __restrict__ ss,
        const u16* __restrict__ WlP, const u16* __restrict__ WrP,
        const float* __restrict__ bl, u16* __restrict__ A, u8* __restrict__ Aq,
        u16* __restrict__ Tout)
{
    const int lane = threadIdx.x & 63;
    const int wave = threadIdx.x >> 6;
    const int nb = blockIdx.x * 64 + wave * 16;
    const int m = lane & 15, q = lane >> 4;
    const int n = nb + m;
    const bool vld = n < N_NODES;
    const int nc = vld ? n : N_NODES - 1;

    Frag fT[4], fX[4];
    gather_frags_q(srcq, ss, rs[nc], rs[nc + 1], q, fT);
    if (vld) {
        // store in the SAME permuted layout load_frags expects
        u16* tp = Tout + (size_t)n * DIM + q * 16;
        *(uint4*)(tp)      = fT[0].ui;
        *(uint4*)(tp + 8)  = fT[1].ui;
        *(uint4*)(tp + 64) = fT[2].ui;
        *(uint4*)(tp + 72) = fT[3].ui;
    }
    load_frags(src + (size_t)nc * DIM, q, fX);

    const int col = m;
    const int rowb = q * 4;
    for (int c = 0; c < 8; ++c) {
        f32x4 a = {0.f, 0.f, 0.f, 0.f};
        #pragma unroll
        for (int t = 0; t < 4; ++t) {
            Frag wl, wr;
            wl.ui = *(const uint4*)(WlP + ((c * 4 + t) * 64 + lane) * 8);
            wr.ui = *(const uint4*)(WrP + ((c * 4 + t) * 64 + lane) * 8);
            a = __builtin_amdgcn_mfma_f32_16x16x32_bf16(fT[t].v, wl.v, a, 0, 0, 0);
            a = __builtin_amdgcn_mfma_f32_16x16x32_bf16(fX[t].v, wr.v, a, 0, 0, 0);
        }
        float bias = bl[c * 16 + col];
        #pragma unroll
        for (int r2 = 0; r2 < 4; ++r2) {
            int nr = nb + rowb + r2;
            if (nr < N_NODES) {
                float v = fmaxf(a[r2] + bias, 0.f);
                if (A) A[(size_t)nr * DIM + c * 16 + col] = f2b(v);
                u32 q8 = 0;
                q8 = __builtin_amdgcn_cvt_pk_fp8_f32(v, v, q8, false);
                Aq[(size_t)nr * DIM + c * 16 + col] = (u8)(q8 & 0xff);
            }
        }
    }
}

// xm_new = r*relu(Ta@Wl+b+S) + (1-r)*relu(Tb@Wl+b+S), S = xm@Wr (computed once)
template<bool GATHER_A>
__global__ __launch_bounds__(256) void sage_main(
        const u8* __restrict__ srcq, const u16* __restrict__ Tpre,
        const u16* __restrict__ xm,
        const int* __restrict__ rs_a, const int* __restrict__ ss_a,
        const int* __restrict__ rs_b, const int* __restrict__ ss_b,
        const u16* __restrict__ WlP, const u16* __restrict__ WrP,
        const float* __restrict__ bl, const float* __restrict__ rp,
        u16* __restrict__ xout)
{
    const int lane = threadIdx.x & 63;
    const int wave = threadIdx.x >> 6;
    const int nb = blockIdx.x * 64 + wave * 16;
    const int m = lane & 15, q = lane >> 4;
    const int n = nb + m;
    const bool vld = n < N_NODES;
    const int nc = vld ? n : N_NODES - 1;

    Frag fA[4], fB[4], fX[4];
    if (GATHER_A)
        gather_frags_q(srcq, ss_a, rs_a[nc], rs_a[nc + 1], q, fA);
    else
        load_frags(Tpre + (size_t)nc * DIM, q, fA);
    gather_frags_q(srcq, ss_b, rs_b[nc], rs_b[nc + 1], q, fB);
    load_frags(xm + (size_t)nc * DIM, q, fX);
    float r = *rp;

    const int col = m;
    const int rowb = q * 4;
    for (int c = 0; c < 8; ++c) {
        f32x4 s = {0.f, 0.f, 0.f, 0.f};
        Frag wl[4];
        #pragma unroll
        for (int t = 0; t < 4; ++t) {
            Frag wr;
            wr.ui = *(const uint4*)(WrP + ((c * 4 + t) * 64 + lane) * 8);
            wl[t].ui = *(const uint4*)(WlP + ((c * 4 + t) * 64 + lane) * 8);
            s = __builtin_amdgcn_mfma_f32_16x16x32_bf16(fX[t].v, wr.v, s, 0, 0, 0);
        }
        f32x4 pa = s, pb = s;
        #pragma unroll
        for (int t = 0; t < 4; ++t)
            pa = __builtin_amdgcn_mfma_f32_16x16x32_bf16(fA[t].v, wl[t].v, pa, 0, 0, 0);
        #pragma unroll
        for (int t = 0; t < 4; ++t)
            pb = __builtin_amdgcn_mfma_f32_16x16x32_bf16(fB[t].v, wl[t].v, pb, 0, 0, 0);
        float bias = bl[c * 16 + col];
        #pragma unroll
        for (int r2 = 0; r2 < 4; ++r2) {
            int nr = nb + rowb + r2;
            if (nr < N_NODES) {
                float va = fmaxf(pa[r2] + bias, 0.f);
                float vb = fmaxf(pb[r2] + bias, 0.f);
                xout[(size_t)nr * DIM + c * 16 + col] = f2b(r * va + (1.f - r) * vb);
            }
        }
    }
}

// coalesced bf16 row -> fp32 LDS row (64 lanes x 2 feats)
__device__ __forceinline__ void load_row(const u16* __restrict__ row, int lane,
                                         float* __restrict__ ldsrow) {
    u32 v = *(const u32*)(row + lane * 2);
    ldsrow[lane * 2]     = b2f_lo(v);
    ldsrow[lane * 2 + 1] = b2f_hi(v);
}

// logits + log_softmax; 4 waves/block, one node per wave
__global__ __launch_bounds__(256) void out_kernel(const u16* __restrict__ xm,
        const float* __restrict__ Wo, const float* __restrict__ bo,
        float* __restrict__ out) {
    __shared__ float row[4][DIM];
    const int wave = threadIdx.x >> 6;
    const int lane = threadIdx.x & 63;
    const int n = blockIdx.x * 4 + wave;
    load_row(xm + (size_t)n * DIM, lane, row[wave]);
    float acc = -1e30f;
    if (lane < NCLS) {
        acc = bo[lane];
        #pragma unroll 4
        for (int k = 0; k < DIM; ++k) acc += row[wave][k] * Wo[k * NCLS + lane];
    }
    float mx = acc;
    for (int o = 32; o > 0; o >>= 1) mx = fmaxf(mx, __shfl_xor(mx, o, 64));
    float e = (lane < NCLS) ? expf(acc - mx) : 0.f;
    float sum = e;
    for (int o = 32; o > 0; o >>= 1) sum += __shfl_xor(sum, o, 64);
    if (lane < NCLS) out[(size_t)n * NCLS + lane] = acc - mx - logf(sum);
}

// ---------------- driver ----------------

extern "C" void kernel_launch(void* const* d_in, const int* in_sizes, int n_in,
                              void* d_out, int out_size, void* d_ws, size_t ws_size,
                              hipStream_t stream) {
    const float* x    = (const float*)d_in[0];
    const float* Wl   = (const float*)d_in[1];
    const float* bl   = (const float*)d_in[2];
    const float* Wr   = (const float*)d_in[3];
    const float* Wo   = (const float*)d_in[4];
    const float* bo   = (const float*)d_in[5];
    const float* rp   = (const float*)d_in[6];
    const int*   adj  = (const int*)d_in[7];
    const int*   adjb = (const int*)d_in[8];
    const int*   perm = (const int*)d_in[9];
    float* out = (float*)d_out;

    char* ws = (char*)d_ws;
    size_t off = 0;
    auto alloc = [&](size_t bytes) {
        char* p = ws + off;
        off += (bytes + 255) & ~(size_t)255;
        return p;
    };
    int* rs_a   = (int*)alloc((N_NODES + 1) * 4);
    int* rs_b   = (int*)alloc((N_NODES + 1) * 4);
    int* ss_a   = (int*)alloc((size_t)N_EDGES * 4);
    int* ss_b   = (int*)alloc((size_t)N_EDGES * 4);
    int* cur2   = (int*)alloc((size_t)2 * N_NODES * 4);   // curA | curB contiguous
    int* bsums  = (int*)alloc(1024 * 4);                  // bsA(512) | bsB(512)
    u16* WlP    = (u16*)alloc(3 * 16384 * 2);
    u16* WrP    = (u16*)alloc(3 * 16384 * 2);
    const size_t FB = (size_t)N_NODES * DIM * 2;   // bf16 feature buffer (25.6 MB)
    const size_t QB = (size_t)N_NODES * DIM;       // fp8  feature buffer (12.8 MB)
    u16* xb  = (u16*)alloc(FB);    // bf16 x; re-used as A2q after last read
    u16* xm0 = (u16*)alloc(FB);
    u16* A1  = (u16*)alloc(FB);
    u16* T0  = (u16*)alloc(FB);    // aliased as xm1 (row-for-row safe)
    u16* T1  = (u16*)alloc(FB);
    u8*  xq  = (u8*)alloc(QB);
    u8*  A1q = (u8*)alloc(QB);
    u16* xm1 = T0;
    u8*  A2q = (u8*)xb;            // alias: xb's last read (pre1 fX) precedes pre2's write
    int* curA = cur2, *curB = cur2 + N_NODES;
    int* bsA = bsums, *bsB = bsums + 512;

    const int nbE = (N_EDGES + 255) / 256;
    const int nbN = (N_NODES + 255) / 256;   // 391

    // CSR build, both graphs per launch
    hipMemsetAsync(cur2, 0, (size_t)2 * N_NODES * 4, stream);
    hist2<<<2 * nbE, 256, 0, stream>>>(adj + N_EDGES, adjb + N_EDGES, curA, curB, N_EDGES);
    scan_blocks2<<<2 * nbN, 256, 0, stream>>>(curA, curB, rs_a, rs_b, bsA, bsB,
                                              N_NODES, nbN);
    scan_small2<<<2, 512, 0, stream>>>(bsA, bsB, nbN);
    add_offsets2<<<2 * nbN, 256, 0, stream>>>(rs_a, rs_b, bsA, bsB, N_NODES, nbN, N_EDGES);
    hipMemsetAsync(cur2, 0, (size_t)2 * N_NODES * 4, stream);
    scatter2<<<2 * nbE, 256, 0, stream>>>(adj, adjb, rs_a, rs_b, curA, curB,
                                          ss_a, ss_b, perm, N_EDGES);

    // weight packing + input conversion/mix
    pack_weights<<<192, 256, 0, stream>>>(Wl, Wr, WlP, WrP);
    conv_mix<<<(N_NODES * DIM) / 1024, 256, 0, stream>>>(x, perm, rp, xb, xm0, xq);

    const int WP = 16384;                 // packed per-layer weight stride (u16)
    const int nbS = (N_NODES + 63) / 64;  // 1563 blocks, 64 nodes each

    // pre passes (save aggregations T0 = agg_a(x), T1 = agg_a(A1))
    sage_pre<<<nbS, 256, 0, stream>>>(xq, xb, rs_a, ss_a, WlP, WrP, bl,
                                      A1, A1q, T0);
    sage_pre<<<nbS, 256, 0, stream>>>(A1q, A1, rs_a, ss_a, WlP + WP, WrP + WP,
                                      bl + DIM, nullptr, A2q, T1);

    // main layers: 0/1 reuse T0/T1; layer 2 gathers both branches (fp8)
    sage_main<false><<<nbS, 256, 0, stream>>>(xq, T0, xm0, rs_a, ss_a, rs_b, ss_b,
        WlP, WrP, bl, rp, xm1);
    sage_main<false><<<nbS, 256, 0, stream>>>(A1q, T1, xm1, rs_a, ss_a, rs_b, ss_b,
        WlP + WP, WrP + WP, bl + DIM, rp, xm0);
    sage_main<true><<<nbS, 256, 0, stream>>>(A2q, nullptr, xm0, rs_a, ss_a, rs_b, ss_b,
        WlP + 2 * WP, WrP + 2 * WP, bl + 2 * DIM, rp, xm1);

    out_kernel<<<N_NODES / 4, 256, 0, stream>>>(xm1, Wo, bo, out);
}

// Round 7
// 901.644 us; speedup vs baseline: 3.0193x; 1.1515x over previous
//
#include <hip/hip_runtime.h>
#include <math.h>

#define N_NODES 100000
#define N_EDGES 1600000
#define DIM 128
#define NCLS 40
#define NSHARD 8
#define SHARD_SZ (N_NODES / NSHARD)   // 12500

typedef unsigned short u16;
typedef unsigned int u32;
typedef unsigned char u8;
typedef __attribute__((ext_vector_type(8))) short bf16x8;
typedef __attribute__((ext_vector_type(4))) float f32x4;
typedef __attribute__((ext_vector_type(2))) float f32x2;

union Frag { bf16x8 v; u16 u[8]; uint4 ui; };

__device__ __forceinline__ float b2f_lo(u32 u){ union{u32 i;float f;}c; c.i=u<<16; return c.f; }
__device__ __forceinline__ float b2f_hi(u32 u){ union{u32 i;float f;}c; c.i=u&0xffff0000u; return c.f; }
__device__ __forceinline__ u16 f2b(float f){ union{float f;u32 i;}c; c.f=f; u32 r=c.i+0x7fffu+((c.i>>16)&1u); return (u16)(r>>16); }

// fp8 e4m3 (OCP) pack/unpack via HW converts
__device__ __forceinline__ u32 pack4_fp8(float a, float b, float c, float d) {
    u32 v = 0;
    v = __builtin_amdgcn_cvt_pk_fp8_f32(a, b, v, false);
    v = __builtin_amdgcn_cvt_pk_fp8_f32(c, d, v, true);
    return v;
}
__device__ __forceinline__ void addq(float* a, u32 w) {
    f32x2 p0 = __builtin_amdgcn_cvt_pk_f32_fp8(w, false);
    f32x2 p1 = __builtin_amdgcn_cvt_pk_f32_fp8(w, true);
    a[0] += p0.x; a[1] += p0.y; a[2] += p1.x; a[3] += p1.y;
}

// ---------------- CSR build ----------------

__global__ void hist2(const int* __restrict__ dA, const int* __restrict__ dB,
                      int* __restrict__ cA, int* __restrict__ cB, int E) {
    int e = blockIdx.x * blockDim.x + threadIdx.x;
    if (e < E) atomicAdd(&cA[dA[e]], 1);
    else { e -= E; if (e < E) atomicAdd(&cB[dB[e]], 1); }
}

__global__ void scan_blocks2(const int* __restrict__ inA, const int* __restrict__ inB,
                             int* __restrict__ outA, int* __restrict__ outB,
                             int* __restrict__ bsA, int* __restrict__ bsB,
                             int n, int nb) {
    __shared__ int s[256];
    int half = blockIdx.x >= nb, b = blockIdx.x - half * nb;
    const int* in = half ? inB : inA;
    int* out = half ? outB : outA;
    int* bs  = half ? bsB  : bsA;
    int i = b * 256 + threadIdx.x;
    int v = (i < n) ? in[i] : 0;
    s[threadIdx.x] = v;
    __syncthreads();
    for (int d = 1; d < 256; d <<= 1) {
        int t = (threadIdx.x >= d) ? s[threadIdx.x - d] : 0;
        __syncthreads();
        s[threadIdx.x] += t;
        __syncthreads();
    }
    if (i < n) out[i] = s[threadIdx.x] - v;
    if (threadIdx.x == 255) bs[b] = s[255];
}

__global__ void scan_small2(int* __restrict__ bsA, int* __restrict__ bsB, int n) {
    __shared__ int s[512];
    int* data = blockIdx.x ? bsB : bsA;
    int v = (threadIdx.x < n) ? data[threadIdx.x] : 0;
    s[threadIdx.x] = v;
    __syncthreads();
    for (int d = 1; d < 512; d <<= 1) {
        int t = (threadIdx.x >= d) ? s[threadIdx.x - d] : 0;
        __syncthreads();
        s[threadIdx.x] += t;
        __syncthreads();
    }
    if (threadIdx.x < n) data[threadIdx.x] = s[threadIdx.x] - v;
}

__global__ void add_offsets2(int* __restrict__ rsA, int* __restrict__ rsB,
                             const int* __restrict__ bsA, const int* __restrict__ bsB,
                             int n, int nb, int total) {
    int half = blockIdx.x >= nb, b = blockIdx.x - half * nb;
    int* rs = half ? rsB : rsA;
    const int* bs = half ? bsB : bsA;
    int i = b * 256 + threadIdx.x;
    if (i < n) rs[i] += bs[b];
    if (b == 0 && threadIdx.x == 0) rs[n] = total;
}

// XCD-sharded scatter: class = blockIdx&7 handles dst in [cls*12500,(cls+1)*12500).
// All of a class's ss writes land in one ~800KB region -> stays hot in the owning
// XCD's L2 until lines are fully populated (kills the 17x writeback amplification).
// Correct regardless of the actual block->XCD mapping (locality heuristic only).
__global__ void scatter_sharded(const int* __restrict__ adjA, const int* __restrict__ adjB,
        const int* __restrict__ rsA, const int* __restrict__ rsB,
        int* __restrict__ curA, int* __restrict__ curB,
        int* __restrict__ ssA, int* __restrict__ ssB,
        const int* __restrict__ perm, int E) {
    const int cls = blockIdx.x & 7;
    const int lo = cls * SHARD_SZ, hi = lo + SHARD_SZ;
    int i = (blockIdx.x >> 3) * blockDim.x + threadIdx.x;   // [0, 2E)
    if (i < E) {
        int d = adjA[E + i];
        if (d >= lo && d < hi) {
            int p = atomicAdd(&curA[d], 1);
            ssA[rsA[d] + p] = adjA[i];
        }
    } else {
        i -= E;
        if (i < E) {
            int d = adjB[E + i];
            if (d >= lo && d < hi) {
                int p = atomicAdd(&curB[d], 1);
                ssB[rsB[d] + p] = perm[adjB[i]];   // perm folded into branch-b sources
            }
        }
    }
}

// xb = bf16(x); xq = fp8(x); xm0 = bf16(r*x + (1-r)*x[perm])  — 4 elems/thread
__global__ void conv_mix(const float* __restrict__ x, const int* __restrict__ perm,
                         const float* __restrict__ rp, u16* __restrict__ xb,
                         u16* __restrict__ xm, u8* __restrict__ xq) {
    int i = (blockIdx.x * 256 + threadIdx.x) * 4;
    int n = i >> 7, f = i & 127;
    float r = *rp;
    int p = perm[n];
    float4 xv = *(const float4*)(x + i);
    float4 pv = *(const float4*)(x + (size_t)p * DIM + f);
    ushort4 b, m;
    b.x = f2b(xv.x); b.y = f2b(xv.y); b.z = f2b(xv.z); b.w = f2b(xv.w);
    m.x = f2b(r * xv.x + (1.f - r) * pv.x);
    m.y = f2b(r * xv.y + (1.f - r) * pv.y);
    m.z = f2b(r * xv.z + (1.f - r) * pv.z);
    m.w = f2b(r * xv.w + (1.f - r) * pv.w);
    *(ushort4*)(xb + i) = b;
    *(ushort4*)(xm + i) = m;
    *(u32*)(xq + i) = pack4_fp8(xv.x, xv.y, xv.z, xv.w);
}

// pack W fp32 -> bf16 B-fragment order, k-PERMUTED mapping:
// frag (c, t, lane l (q=l>>4, n=l&15), j) holds W[k][c*16+n],
//   k = (t>>1)*64 + q*16 + (t&1)*8 + j   (matches the 2x16B-per-edge gather layout)
__global__ void pack_weights(const float* __restrict__ Wl, const float* __restrict__ Wr,
                             u16* __restrict__ WlP, u16* __restrict__ WrP) {
    int i = blockIdx.x * 256 + threadIdx.x;          // [0, 3*16384)
    int layer = i >> 14, idx = i & 16383;
    int j = idx & 7, l = (idx >> 3) & 63, t = (idx >> 9) & 3, c = idx >> 11;
    int k = ((t >> 1) << 6) + (((l >> 4)) << 4) + ((t & 1) << 3) + j;
    int col = (c << 4) + (l & 15);
    WlP[i] = f2b(Wl[layer * 16384 + k * DIM + col]);
    WrP[i] = f2b(Wr[layer * 16384 + k * DIM + col]);
}

// ---------------- fp8 gather, 2x16B per edge (request-minimal) ----------------

__device__ __forceinline__ void gather_frags_q(const u8* __restrict__ src,
        const int* __restrict__ ss, int beg, int end, int q, Frag* f) {
    float acc[32];
    #pragma unroll
    for (int j = 0; j < 32; ++j) acc[j] = 0.f;
    const u8* s0 = src + q * 16;
    const u8* s1 = src + 64 + q * 16;
    #pragma unroll 4
    for (int e = beg; e < end; ++e) {
        int s = ss[e];
        uint4 v0 = *(const uint4*)(s0 + (size_t)s * DIM);
        uint4 v1 = *(const uint4*)(s1 + (size_t)s * DIM);
        addq(acc +  0, v0.x); addq(acc +  4, v0.y);
        addq(acc +  8, v0.z); addq(acc + 12, v0.w);
        addq(acc + 16, v1.x); addq(acc + 20, v1.y);
        addq(acc + 24, v1.z); addq(acc + 28, v1.w);
    }
    float inv = (end > beg) ? 1.f / (float)(end - beg) : 0.f;
    #pragma unroll
    for (int t = 0; t < 4; ++t)
        #pragma unroll
        for (int j = 0; j < 8; ++j) f[t].u[j] = f2b(acc[t * 8 + j] * inv);
}

// bf16 direct row (standard order) -> frags, same k-permuted slot mapping
__device__ __forceinline__ void load_frags(const u16* __restrict__ row, int q, Frag* f) {
    const u16* p = row + q * 16;
    f[0].ui = *(const uint4*)(p);
    f[1].ui = *(const uint4*)(p + 8);
    f[2].ui = *(const uint4*)(p + 64);
    f[3].ui = *(const uint4*)(p + 72);
}

// ---------------- fused sage layer: pre-pass + dual-branch main in one pass ----
// 1 wave = 16 nodes, zero LDS.
// u = Ta@Wl (shared by A_next and branch-a), s = xm@Wr:
//   A_next = relu(u + X@Wr + b)          (HAS_A)
//   xm_out = r*relu(u+s+b) + (1-r)*relu(Tb@Wl+s+b)     [pa = u+s is a free vadd]
template<bool HAS_A>
__global__ __launch_bounds__(256) void sage_layer(
        const u8* __restrict__ srcq, const u16* __restrict__ srcb,
        const u16* __restrict__ xm,
        const int* __restrict__ rs_a, const int* __restrict__ ss_a,
        const int* __restrict__ rs_b, const int* __restrict__ ss_b,
        const u16* __restrict__ WlP, const u16* __restrict__ WrP,
        const float* __restrict__ bl, const float* __restrict__ rp,
        u16* __restrict__ Aout, u8* __restrict__ Aqout, u16* __restrict__ xmout)
{
    const int lane = threadIdx.x & 63;
    const int wave = threadIdx.x >> 6;
    const int nb = blockIdx.x * 64 + wave * 16;
    const int m = lane & 15, q = lane >> 4;
    const int n = nb + m;
    const bool vld = n < N_NODES;
    const int nc = vld ? n : N_NODES - 1;

    Frag fA[4], fB[4], fX[4], fM[4];
    gather_frags_q(srcq, ss_a, rs_a[nc], rs_a[nc + 1], q, fA);
    gather_frags_q(srcq, ss_b, rs_b[nc], rs_b[nc + 1], q, fB);
    if (HAS_A) load_frags(srcb + (size_t)nc * DIM, q, fX);
    load_frags(xm + (size_t)nc * DIM, q, fM);
    float r = *rp;

    const int col = m;
    const int rowb = q * 4;
    for (int c = 0; c < 8; ++c) {
        Frag wl[4], wr[4];
        #pragma unroll
        for (int t = 0; t < 4; ++t) {
            wl[t].ui = *(const uint4*)(WlP + ((c * 4 + t) * 64 + lane) * 8);
            wr[t].ui = *(const uint4*)(WrP + ((c * 4 + t) * 64 + lane) * 8);
        }
        f32x4 u = {0.f, 0.f, 0.f, 0.f};
        #pragma unroll
        for (int t = 0; t < 4; ++t)
            u = __builtin_amdgcn_mfma_f32_16x16x32_bf16(fA[t].v, wl[t].v, u, 0, 0, 0);
        f32x4 s = {0.f, 0.f, 0.f, 0.f};
        #pragma unroll
        for (int t = 0; t < 4; ++t)
            s = __builtin_amdgcn_mfma_f32_16x16x32_bf16(fM[t].v, wr[t].v, s, 0, 0, 0);
        f32x4 pb = s;
        #pragma unroll
        for (int t = 0; t < 4; ++t)
            pb = __builtin_amdgcn_mfma_f32_16x16x32_bf16(fB[t].v, wl[t].v, pb, 0, 0, 0);
        f32x4 aA;
        if (HAS_A) {
            aA = u;
            #pragma unroll
            for (int t = 0; t < 4; ++t)
                aA = __builtin_amdgcn_mfma_f32_16x16x32_bf16(fX[t].v, wr[t].v, aA, 0, 0, 0);
        }
        f32x4 pa = u + s;
        float bias = bl[c * 16 + col];
        #pragma unroll
        for (int r2 = 0; r2 < 4; ++r2) {
            int nr = nb + rowb + r2;
            if (nr < N_NODES) {
                if (HAS_A) {
                    float v = fmaxf(aA[r2] + bias, 0.f);
                    if (Aout) Aout[(size_t)nr * DIM + c * 16 + col] = f2b(v);
                    u32 q8 = 0;
                    q8 = __builtin_amdgcn_cvt_pk_fp8_f32(v, v, q8, false);
                    Aqout[(size_t)nr * DIM + c * 16 + col] = (u8)(q8 & 0xff);
                }
                float va = fmaxf(pa[r2] + bias, 0.f);
                float vb = fmaxf(pb[r2] + bias, 0.f);
                xmout[(size_t)nr * DIM + c * 16 + col] = f2b(r * va + (1.f - r) * vb);
            }
        }
    }
}

// coalesced bf16 row -> fp32 LDS row (64 lanes x 2 feats)
__device__ __forceinline__ void load_row(const u16* __restrict__ row, int lane,
                                         float* __restrict__ ldsrow) {
    u32 v = *(const u32*)(row + lane * 2);
    ldsrow[lane * 2]     = b2f_lo(v);
    ldsrow[lane * 2 + 1] = b2f_hi(v);
}

// logits + log_softmax; 4 waves/block, one node per wave
__global__ __launch_bounds__(256) void out_kernel(const u16* __restrict__ xm,
        const float* __restrict__ Wo, const float* __restrict__ bo,
        float* __restrict__ out) {
    __shared__ float row[4][DIM];
    const int wave = threadIdx.x >> 6;
    const int lane = threadIdx.x & 63;
    const int n = blockIdx.x * 4 + wave;
    load_row(xm + (size_t)n * DIM, lane, row[wave]);
    float acc = -1e30f;
    if (lane < NCLS) {
        acc = bo[lane];
        #pragma unroll 4
        for (int k = 0; k < DIM; ++k) acc += row[wave][k] * Wo[k * NCLS + lane];
    }
    float mx = acc;
    for (int o = 32; o > 0; o >>= 1) mx = fmaxf(mx, __shfl_xor(mx, o, 64));
    float e = (lane < NCLS) ? expf(acc - mx) : 0.f;
    float sum = e;
    for (int o = 32; o > 0; o >>= 1) sum += __shfl_xor(sum, o, 64);
    if (lane < NCLS) out[(size_t)n * NCLS + lane] = acc - mx - logf(sum);
}

// ---------------- driver ----------------

extern "C" void kernel_launch(void* const* d_in, const int* in_sizes, int n_in,
                              void* d_out, int out_size, void* d_ws, size_t ws_size,
                              hipStream_t stream) {
    const float* x    = (const float*)d_in[0];
    const float* Wl   = (const float*)d_in[1];
    const float* bl   = (const float*)d_in[2];
    const float* Wr   = (const float*)d_in[3];
    const float* Wo   = (const float*)d_in[4];
    const float* bo   = (const float*)d_in[5];
    const float* rp   = (const float*)d_in[6];
    const int*   adj  = (const int*)d_in[7];
    const int*   adjb = (const int*)d_in[8];
    const int*   perm = (const int*)d_in[9];
    float* out = (float*)d_out;

    char* ws = (char*)d_ws;
    size_t off = 0;
    auto alloc = [&](size_t bytes) {
        char* p = ws + off;
        off += (bytes + 255) & ~(size_t)255;
        return p;
    };
    int* rs_a   = (int*)alloc((N_NODES + 1) * 4);
    int* rs_b   = (int*)alloc((N_NODES + 1) * 4);
    int* ss_a   = (int*)alloc((size_t)N_EDGES * 4);
    int* ss_b   = (int*)alloc((size_t)N_EDGES * 4);
    int* cur2   = (int*)alloc((size_t)2 * N_NODES * 4);   // curA | curB contiguous
    int* bsums  = (int*)alloc(1024 * 4);                  // bsA(512) | bsB(512)
    u16* WlP    = (u16*)alloc(3 * 16384 * 2);
    u16* WrP    = (u16*)alloc(3 * 16384 * 2);
    const size_t FB = (size_t)N_NODES * DIM * 2;   // bf16 feature buffer (25.6 MB)
    const size_t QB = (size_t)N_NODES * DIM;       // fp8  feature buffer (12.8 MB)
    u16* xb  = (u16*)alloc(FB);
    u16* xm0 = (u16*)alloc(FB);
    u16* A1  = (u16*)alloc(FB);
    u16* xm1 = (u16*)alloc(FB);
    u8*  xq  = (u8*)alloc(QB);
    u8*  A1q = (u8*)alloc(QB);
    // aliases (no same-kernel read/write overlap anywhere):
    u16* xm2 = xb;          // xb last read in L0; L1 writes xm2, L2 reads
    u8*  A2q = (u8*)xm0;    // xm0 last read in L0; L1 writes A2q, L2 reads
    u16* xm3 = A1;          // A1 last read in L1; L2 writes xm3, out reads
    int* curA = cur2, *curB = cur2 + N_NODES;
    int* bsA = bsums, *bsB = bsums + 512;
    // total ws use ~130 MB

    const int nbE = (N_EDGES + 255) / 256;
    const int nbN = (N_NODES + 255) / 256;   // 391

    // CSR build, both graphs per launch
    hipMemsetAsync(cur2, 0, (size_t)2 * N_NODES * 4, stream);
    hist2<<<2 * nbE, 256, 0, stream>>>(adj + N_EDGES, adjb + N_EDGES, curA, curB, N_EDGES);
    scan_blocks2<<<2 * nbN, 256, 0, stream>>>(curA, curB, rs_a, rs_b, bsA, bsB,
                                              N_NODES, nbN);
    scan_small2<<<2, 512, 0, stream>>>(bsA, bsB, nbN);
    add_offsets2<<<2 * nbN, 256, 0, stream>>>(rs_a, rs_b, bsA, bsB, N_NODES, nbN, N_EDGES);
    hipMemsetAsync(cur2, 0, (size_t)2 * N_NODES * 4, stream);
    scatter_sharded<<<NSHARD * 2 * nbE, 256, 0, stream>>>(adj, adjb, rs_a, rs_b,
        curA, curB, ss_a, ss_b, perm, N_EDGES);

    // weight packing + input conversion/mix
    pack_weights<<<192, 256, 0, stream>>>(Wl, Wr, WlP, WrP);
    conv_mix<<<(N_NODES * DIM) / 1024, 256, 0, stream>>>(x, perm, rp, xb, xm0, xq);

    const int WP = 16384;                 // packed per-layer weight stride (u16)
    const int nbS = (N_NODES + 63) / 64;  // 1563 blocks, 64 nodes each

    // fused layers (pre-pass + dual-branch main per layer)
    sage_layer<true><<<nbS, 256, 0, stream>>>(xq, xb, xm0,
        rs_a, ss_a, rs_b, ss_b, WlP, WrP, bl, rp, A1, A1q, xm1);
    sage_layer<true><<<nbS, 256, 0, stream>>>(A1q, A1, xm1,
        rs_a, ss_a, rs_b, ss_b, WlP + WP, WrP + WP, bl + DIM, rp,
        nullptr, A2q, xm2);
    sage_layer<false><<<nbS, 256, 0, stream>>>(A2q, nullptr, xm2,
        rs_a, ss_a, rs_b, ss_b, WlP + 2 * WP, WrP + 2 * WP, bl + 2 * DIM, rp,
        nullptr, nullptr, xm3);

    out_kernel<<<N_NODES / 4, 256, 0, stream>>>(xm3, Wo, bo, out);
}